// Round 4
// baseline (522.417 us; speedup 1.0000x reference)
//
#include <hip/hip_runtime.h>
#include <hip/hip_bf16.h>

// GCN via device-built CSR (by dst, precomputed edge norms, atomicExch payload
// writes for L2/MALL line assembly) + bf16 feature storage (fp32 accumulate).

#define N_NODES 131072
#define N_EDGES 2097152
#define N_GRAPHS 2048
#define IN_CH 12
#define HID 64
#define OUT_CH 4

__device__ __forceinline__ unsigned short f2bf(float f) {
    unsigned u = __float_as_uint(f);
    return (unsigned short)((u + 0x7fffu + ((u >> 16) & 1u)) >> 16);  // RNE
}
__device__ __forceinline__ float bf2f(unsigned short b) {
    return __uint_as_float((unsigned)b << 16);
}

// ---- in-degree histogram ----
__global__ void hist_kernel(const int* __restrict__ dst, int* __restrict__ cnt) {
    int e = blockIdx.x * 256 + threadIdx.x;
    atomicAdd(&cnt[dst[e]], 1);
}

// ---- scan phase 1: per-block exclusive scan + block sums; also dinv ----
__global__ void scan1_kernel(const int* __restrict__ cnt, int* __restrict__ rowptr,
                             int* __restrict__ bsum, float* __restrict__ dinv) {
    __shared__ int tmp[256];
    int i = blockIdx.x * 256 + threadIdx.x;
    int v = cnt[i];
    dinv[i] = rsqrtf((float)v + 1.0f);  // +1 self loop
    tmp[threadIdx.x] = v;
    __syncthreads();
    for (int off = 1; off < 256; off <<= 1) {
        int t = (threadIdx.x >= off) ? tmp[threadIdx.x - off] : 0;
        __syncthreads();
        tmp[threadIdx.x] += t;
        __syncthreads();
    }
    rowptr[i] = tmp[threadIdx.x] - v;  // exclusive
    if (threadIdx.x == 255) bsum[blockIdx.x] = tmp[255];
}

// ---- scan phase 2: exclusive scan of 512 block sums ----
__global__ void scan2_kernel(int* __restrict__ bsum) {
    __shared__ int tmp[512];
    int t = threadIdx.x;
    int v = bsum[t];
    tmp[t] = v;
    __syncthreads();
    for (int off = 1; off < 512; off <<= 1) {
        int u = (t >= off) ? tmp[t - off] : 0;
        __syncthreads();
        tmp[t] += u;
        __syncthreads();
    }
    bsum[t] = tmp[t] - v;  // exclusive
}

// ---- scan phase 3: add block offsets; emit rowptr + working copy ----
__global__ void scan3_kernel(int* __restrict__ rowptr, const int* __restrict__ bsum,
                             int* __restrict__ rowptr_work) {
    int i = blockIdx.x * 256 + threadIdx.x;
    int r = rowptr[i] + bsum[blockIdx.x];
    rowptr[i] = r;
    rowptr_work[i] = r;  // fill cursor; after fill == row END pointer
}

// ---- CSR fill: csr[pos] = {src, norm} via 64-bit atomicExch (line assembly) ----
__global__ void fill_kernel(const int* __restrict__ src, const int* __restrict__ dst,
                            const float* __restrict__ dinv, int* __restrict__ rowptr_work,
                            unsigned long long* __restrict__ csr) {
    int e = blockIdx.x * 256 + threadIdx.x;
    int s = src[e], d = dst[e];
    int pos = atomicAdd(&rowptr_work[d], 1);
    unsigned long long p =
        ((unsigned long long)(unsigned)__float_as_uint(dinv[s] * dinv[d]) << 32) | (unsigned)s;
    atomicExch(&csr[pos], p);
}

// ---- shared gather body over bf16 features; all lanes end with full float4 sum ----
__device__ __forceinline__ float4 agg_body(int beg, int end, const int2* __restrict__ csr,
                                           const unsigned short* __restrict__ h,
                                           int sub, int q) {
    float4 a0 = {0, 0, 0, 0}, a1 = {0, 0, 0, 0};
    int j = beg;
    for (; j + 7 < end; j += 8) {
        int2 e0 = csr[j + sub];
        int2 e1 = csr[j + 4 + sub];
        ushort4 u0 = *(const ushort4*)&h[e0.x * HID + 4 * q];
        ushort4 u1 = *(const ushort4*)&h[e1.x * HID + 4 * q];
        float n0 = __int_as_float(e0.y), n1 = __int_as_float(e1.y);
        a0.x += n0 * bf2f(u0.x); a0.y += n0 * bf2f(u0.y);
        a0.z += n0 * bf2f(u0.z); a0.w += n0 * bf2f(u0.w);
        a1.x += n1 * bf2f(u1.x); a1.y += n1 * bf2f(u1.y);
        a1.z += n1 * bf2f(u1.z); a1.w += n1 * bf2f(u1.w);
    }
    for (; j + sub < end; j += 4) {
        int2 e0 = csr[j + sub];
        ushort4 u0 = *(const ushort4*)&h[e0.x * HID + 4 * q];
        float n0 = __int_as_float(e0.y);
        a0.x += n0 * bf2f(u0.x); a0.y += n0 * bf2f(u0.y);
        a0.z += n0 * bf2f(u0.z); a0.w += n0 * bf2f(u0.w);
    }
    float4 acc;
    acc.x = a0.x + a1.x; acc.y = a0.y + a1.y; acc.z = a0.z + a1.z; acc.w = a0.w + a1.w;
    acc.x += __shfl_xor(acc.x, 16, 64); acc.y += __shfl_xor(acc.y, 16, 64);
    acc.z += __shfl_xor(acc.z, 16, 64); acc.w += __shfl_xor(acc.w, 16, 64);
    acc.x += __shfl_xor(acc.x, 32, 64); acc.y += __shfl_xor(acc.y, 32, 64);
    acc.z += __shfl_xor(acc.z, 32, 64); acc.w += __shfl_xor(acc.w, 32, 64);
    return acc;
}

// ---- gather-aggregate + self loop + bias + relu -> bf16 out ----
__global__ void agg_relu_kernel(const int* __restrict__ rowptr, const int* __restrict__ rowend,
                                const int2* __restrict__ csr, const float* __restrict__ dinv,
                                const unsigned short* __restrict__ h,
                                const float* __restrict__ b, unsigned short* __restrict__ out) {
    int tid = threadIdx.x;
    int wid = tid >> 6, lane = tid & 63;
    int sub = lane >> 4, q = lane & 15;
    int node = blockIdx.x * 4 + wid;
    float dn = dinv[node];
    float4 acc = agg_body(rowptr[node], rowend[node], csr, h, sub, q);
    ushort4 su = *(const ushort4*)&h[node * HID + 4 * q];
    float4 bb = *(const float4*)&b[4 * q];
    float dn2 = dn * dn;
    ushort4 v;
    v.x = f2bf(fmaxf(acc.x + dn2 * bf2f(su.x) + bb.x, 0.0f));
    v.y = f2bf(fmaxf(acc.y + dn2 * bf2f(su.y) + bb.y, 0.0f));
    v.z = f2bf(fmaxf(acc.z + dn2 * bf2f(su.z) + bb.z, 0.0f));
    v.w = f2bf(fmaxf(acc.w + dn2 * bf2f(su.w) + bb.w, 0.0f));
    if (sub == 0) *(ushort4*)&out[node * HID + 4 * q] = v;
}

// ---- gather-aggregate + relu + fused mean-pool (pool stays fp32) ----
__global__ void agg_pool_kernel(const int* __restrict__ rowptr, const int* __restrict__ rowend,
                                const int2* __restrict__ csr, const float* __restrict__ dinv,
                                const unsigned short* __restrict__ h,
                                const float* __restrict__ b, const int* __restrict__ batch,
                                float* __restrict__ pool, float* __restrict__ gcnt) {
    __shared__ float red[4][HID];
    __shared__ int gid[4];
    int tid = threadIdx.x;
    int wid = tid >> 6, lane = tid & 63;
    int sub = lane >> 4, q = lane & 15;
    int node = blockIdx.x * 4 + wid;
    float dn = dinv[node];
    float4 acc = agg_body(rowptr[node], rowend[node], csr, h, sub, q);
    ushort4 su = *(const ushort4*)&h[node * HID + 4 * q];
    float4 bb = *(const float4*)&b[4 * q];
    float dn2 = dn * dn;
    float4 v;
    v.x = fmaxf(acc.x + dn2 * bf2f(su.x) + bb.x, 0.0f);
    v.y = fmaxf(acc.y + dn2 * bf2f(su.y) + bb.y, 0.0f);
    v.z = fmaxf(acc.z + dn2 * bf2f(su.z) + bb.z, 0.0f);
    v.w = fmaxf(acc.w + dn2 * bf2f(su.w) + bb.w, 0.0f);
    if (sub == 0) *(float4*)&red[wid][4 * q] = v;
    if (lane == 0) gid[wid] = batch[node];
    __syncthreads();
    if (wid == 0) {
        int c = lane;
        float r0 = red[0][c], r1 = red[1][c], r2 = red[2][c], r3 = red[3][c];
        int g0 = gid[0], g1 = gid[1], g2 = gid[2], g3 = gid[3];
        if (g0 == g3) {
            atomicAdd(&pool[g0 * HID + c], r0 + r1 + r2 + r3);
            if (c == 0) atomicAdd(&gcnt[g0], 4.0f);
        } else {
            atomicAdd(&pool[g0 * HID + c], r0);
            atomicAdd(&pool[g1 * HID + c], r1);
            atomicAdd(&pool[g2 * HID + c], r2);
            atomicAdd(&pool[g3 * HID + c], r3);
            if (c == 0) {
                atomicAdd(&gcnt[g0], 1.0f);
                atomicAdd(&gcnt[g1], 1.0f);
                atomicAdd(&gcnt[g2], 1.0f);
                atomicAdd(&gcnt[g3], 1.0f);
            }
        }
    }
}

// ---- x @ W1 : [N,12] @ [12,64] -> bf16; thread = (node, 4 channels) ----
__global__ void xw1_kernel(const float* __restrict__ x, const float* __restrict__ W1,
                           unsigned short* __restrict__ h) {
    __shared__ float sW[IN_CH * HID];
    __shared__ float sx[16 * IN_CH];
    int tid = threadIdx.x;
    for (int i = tid; i < IN_CH * HID; i += 256) sW[i] = W1[i];
    int node0 = blockIdx.x * 16;
    if (tid < 16 * IN_CH) sx[tid] = x[node0 * IN_CH + tid];
    __syncthreads();
    int nl = tid >> 4, c4 = (tid & 15) * 4;
    float a0 = 0, a1 = 0, a2 = 0, a3 = 0;
#pragma unroll
    for (int k = 0; k < IN_CH; k++) {
        float xv = sx[nl * IN_CH + k];
        const float* w = &sW[k * HID + c4];
        a0 += xv * w[0]; a1 += xv * w[1]; a2 += xv * w[2]; a3 += xv * w[3];
    }
    ushort4 v = {f2bf(a0), f2bf(a1), f2bf(a2), f2bf(a3)};
    *(ushort4*)&h[(node0 + nl) * HID + c4] = v;
}

// ---- h @ W2 : [N,64] @ [64,64], bf16 in/out, fp32 compute ----
__global__ void hw2_kernel(const unsigned short* __restrict__ hin,
                           const float* __restrict__ W2, unsigned short* __restrict__ hout) {
    __shared__ float sW[HID * HID];                // 16 KB
    __shared__ __align__(16) float sh[16 * HID];   // 4 KB
    int tid = threadIdx.x;
    for (int i = tid; i < HID * HID; i += 256) sW[i] = W2[i];
    int node0 = blockIdx.x * 16;
    {
        ushort4 u = *(const ushort4*)&hin[node0 * HID + 4 * tid];
        sh[4 * tid + 0] = bf2f(u.x); sh[4 * tid + 1] = bf2f(u.y);
        sh[4 * tid + 2] = bf2f(u.z); sh[4 * tid + 3] = bf2f(u.w);
    }
    __syncthreads();
    int nl = tid >> 4, c4 = (tid & 15) * 4;
    float a0 = 0, a1 = 0, a2 = 0, a3 = 0;
#pragma unroll 8
    for (int k = 0; k < HID; k++) {
        float hv = sh[nl * HID + k];
        float4 w = *(const float4*)&sW[k * HID + c4];
        a0 += hv * w.x; a1 += hv * w.y; a2 += hv * w.z; a3 += hv * w.w;
    }
    ushort4 v = {f2bf(a0), f2bf(a1), f2bf(a2), f2bf(a3)};
    *(ushort4*)&hout[(node0 + nl) * HID + c4] = v;
}

// ---- final: out = sigmoid((pool/cnt) @ Wfc + bfc) ----
__global__ void final_kernel(const float* __restrict__ pool, const float* __restrict__ gcnt,
                             const float* __restrict__ Wfc, const float* __restrict__ bfc,
                             float* __restrict__ out) {
    int idx = blockIdx.x * 256 + threadIdx.x;
    if (idx >= N_GRAPHS * OUT_CH) return;
    int g = idx >> 2, o = idx & 3;
    float inv = 1.0f / fmaxf(gcnt[g], 1.0f);
    float acc = bfc[o];
#pragma unroll
    for (int k = 0; k < HID; k++) acc += pool[g * HID + k] * inv * Wfc[k * OUT_CH + o];
    out[idx] = 1.0f / (1.0f + expf(-acc));
}

extern "C" void kernel_launch(void* const* d_in, const int* in_sizes, int n_in,
                              void* d_out, int out_size, void* d_ws, size_t ws_size,
                              hipStream_t stream) {
    const float* x   = (const float*)d_in[0];
    const int* eidx  = (const int*)d_in[1];
    const int* batch = (const int*)d_in[2];
    const float* W1  = (const float*)d_in[3];
    const float* b1  = (const float*)d_in[4];
    const float* W2  = (const float*)d_in[5];
    const float* b2  = (const float*)d_in[6];
    const float* Wfc = (const float*)d_in[7];
    const float* bfc = (const float*)d_in[8];
    float* out = (float*)d_out;

    const int* src = eidx;
    const int* dst = eidx + N_EDGES;

    // workspace layout (~50 MB)
    unsigned short* hA = (unsigned short*)d_ws;              // 16 MB bf16
    unsigned short* hB = hA + (size_t)N_NODES * HID;         // 16 MB bf16
    unsigned long long* csr = (unsigned long long*)(hB + (size_t)N_NODES * HID);  // 16 MB
    float* dinv   = (float*)(csr + N_EDGES);                 // 512 KB
    int*   cnt    = (int*)(dinv + N_NODES);                  // 512 KB (alias rowptr_work)
    int*   rowptr = cnt + N_NODES;                           // 512 KB
    int*   bsum   = rowptr + N_NODES;                        // 2 KB
    float* pool   = (float*)(bsum + 512);                    // 512 KB
    float* gcnt   = pool + N_GRAPHS * HID;                   // 8 KB
    int*   rowptr_work = cnt;

    hipMemsetAsync(cnt, 0, (size_t)N_NODES * 4, stream);
    hipMemsetAsync(pool, 0, (size_t)(N_GRAPHS * HID + N_GRAPHS) * 4, stream);

    // build CSR (by dst) with per-edge norms
    hist_kernel<<<N_EDGES / 256, 256, 0, stream>>>(dst, cnt);
    scan1_kernel<<<N_NODES / 256, 256, 0, stream>>>(cnt, rowptr, bsum, dinv);
    scan2_kernel<<<1, 512, 0, stream>>>(bsum);
    scan3_kernel<<<N_NODES / 256, 256, 0, stream>>>(rowptr, bsum, rowptr_work);
    fill_kernel<<<N_EDGES / 256, 256, 0, stream>>>(src, dst, dinv, rowptr_work, csr);
    // rowptr_work[d] now equals row END pointer

    // layer 1
    xw1_kernel<<<N_NODES / 16, 256, 0, stream>>>(x, W1, hA);
    agg_relu_kernel<<<N_NODES / 4, 256, 0, stream>>>(rowptr, rowptr_work, (const int2*)csr,
                                                     dinv, hA, b1, hB);

    // layer 2 (pool fused; h2 never materialized)
    hw2_kernel<<<N_NODES / 16, 256, 0, stream>>>(hB, W2, hA);
    agg_pool_kernel<<<N_NODES / 4, 256, 0, stream>>>(rowptr, rowptr_work, (const int2*)csr,
                                                     dinv, hA, b2, batch, pool, gcnt);

    // head
    final_kernel<<<(N_GRAPHS * OUT_CH + 255) / 256, 256, 0, stream>>>(pool, gcnt, Wfc, bfc, out);
}

// Round 5
// 446.407 us; speedup vs baseline: 1.1703x; 1.1703x over previous
//
#include <hip/hip_runtime.h>
#include <hip/hip_bf16.h>

// GCN via device-built CSR (by dst, precomputed edge norms). Fill is
// XCD-partitioned (dst>>14 == blockIdx&7) so each CSR line is written from a
// single XCD -> full-line assembly in its L2, killing the 8x partial-line
// write amplification seen in rounds 3/4. Features stored bf16, fp32 math.

#define N_NODES 131072
#define N_EDGES 2097152
#define N_GRAPHS 2048
#define IN_CH 12
#define HID 64
#define OUT_CH 4

__device__ __forceinline__ unsigned short f2bf(float f) {
    unsigned u = __float_as_uint(f);
    return (unsigned short)((u + 0x7fffu + ((u >> 16) & 1u)) >> 16);  // RNE
}
__device__ __forceinline__ float bf2f(unsigned short b) {
    return __uint_as_float((unsigned)b << 16);
}

// ---- in-degree histogram ----
__global__ void hist_kernel(const int* __restrict__ dst, int* __restrict__ cnt) {
    int e = blockIdx.x * 256 + threadIdx.x;
    atomicAdd(&cnt[dst[e]], 1);
}

// ---- scan phase 1: per-block exclusive scan + block sums; also dinv ----
__global__ void scan1_kernel(const int* __restrict__ cnt, int* __restrict__ rowptr,
                             int* __restrict__ bsum, float* __restrict__ dinv) {
    __shared__ int tmp[256];
    int i = blockIdx.x * 256 + threadIdx.x;
    int v = cnt[i];
    dinv[i] = rsqrtf((float)v + 1.0f);  // +1 self loop
    tmp[threadIdx.x] = v;
    __syncthreads();
    for (int off = 1; off < 256; off <<= 1) {
        int t = (threadIdx.x >= off) ? tmp[threadIdx.x - off] : 0;
        __syncthreads();
        tmp[threadIdx.x] += t;
        __syncthreads();
    }
    rowptr[i] = tmp[threadIdx.x] - v;  // exclusive
    if (threadIdx.x == 255) bsum[blockIdx.x] = tmp[255];
}

// ---- scan phase 2: exclusive scan of 512 block sums ----
__global__ void scan2_kernel(int* __restrict__ bsum) {
    __shared__ int tmp[512];
    int t = threadIdx.x;
    int v = bsum[t];
    tmp[t] = v;
    __syncthreads();
    for (int off = 1; off < 512; off <<= 1) {
        int u = (t >= off) ? tmp[t - off] : 0;
        __syncthreads();
        tmp[t] += u;
        __syncthreads();
    }
    bsum[t] = tmp[t] - v;  // exclusive
}

// ---- scan phase 3: add block offsets; emit rowptr + working copy ----
__global__ void scan3_kernel(int* __restrict__ rowptr, const int* __restrict__ bsum,
                             int* __restrict__ rowptr_work) {
    int i = blockIdx.x * 256 + threadIdx.x;
    int r = rowptr[i] + bsum[blockIdx.x];
    rowptr[i] = r;
    rowptr_work[i] = r;  // fill cursor; after fill == row END pointer
}

// ---- XCD-partitioned CSR fill: partition p = blockIdx&7 handles dst>>14 == p ----
__global__ void fill_part_kernel(const int* __restrict__ src, const int* __restrict__ dst,
                                 const float* __restrict__ dinv, int* __restrict__ rowptr_work,
                                 int2* __restrict__ csr) {
    int part = blockIdx.x & 7;
    int base = (blockIdx.x >> 3) * 2048;
#pragma unroll
    for (int i = 0; i < 8; i++) {
        int e = base + i * 256 + threadIdx.x;
        int d = dst[e];
        if ((d >> 14) == part) {
            int s = src[e];
            int pos = atomicAdd(&rowptr_work[d], 1);
            csr[pos] = make_int2(s, __float_as_int(dinv[s] * dinv[d]));
        }
    }
}

// ---- shared gather body over bf16 features; all lanes end with full float4 sum ----
__device__ __forceinline__ float4 agg_body(int beg, int end, const int2* __restrict__ csr,
                                           const unsigned short* __restrict__ h,
                                           int sub, int q) {
    float4 a0 = {0, 0, 0, 0}, a1 = {0, 0, 0, 0};
    int j = beg;
    for (; j + 7 < end; j += 8) {
        int2 e0 = csr[j + sub];
        int2 e1 = csr[j + 4 + sub];
        ushort4 u0 = *(const ushort4*)&h[e0.x * HID + 4 * q];
        ushort4 u1 = *(const ushort4*)&h[e1.x * HID + 4 * q];
        float n0 = __int_as_float(e0.y), n1 = __int_as_float(e1.y);
        a0.x += n0 * bf2f(u0.x); a0.y += n0 * bf2f(u0.y);
        a0.z += n0 * bf2f(u0.z); a0.w += n0 * bf2f(u0.w);
        a1.x += n1 * bf2f(u1.x); a1.y += n1 * bf2f(u1.y);
        a1.z += n1 * bf2f(u1.z); a1.w += n1 * bf2f(u1.w);
    }
    for (; j + sub < end; j += 4) {
        int2 e0 = csr[j + sub];
        ushort4 u0 = *(const ushort4*)&h[e0.x * HID + 4 * q];
        float n0 = __int_as_float(e0.y);
        a0.x += n0 * bf2f(u0.x); a0.y += n0 * bf2f(u0.y);
        a0.z += n0 * bf2f(u0.z); a0.w += n0 * bf2f(u0.w);
    }
    float4 acc;
    acc.x = a0.x + a1.x; acc.y = a0.y + a1.y; acc.z = a0.z + a1.z; acc.w = a0.w + a1.w;
    acc.x += __shfl_xor(acc.x, 16, 64); acc.y += __shfl_xor(acc.y, 16, 64);
    acc.z += __shfl_xor(acc.z, 16, 64); acc.w += __shfl_xor(acc.w, 16, 64);
    acc.x += __shfl_xor(acc.x, 32, 64); acc.y += __shfl_xor(acc.y, 32, 64);
    acc.z += __shfl_xor(acc.z, 32, 64); acc.w += __shfl_xor(acc.w, 32, 64);
    return acc;
}

// ---- gather-aggregate + self loop + bias + relu -> bf16 out ----
__global__ void agg_relu_kernel(const int* __restrict__ rowptr, const int* __restrict__ rowend,
                                const int2* __restrict__ csr, const float* __restrict__ dinv,
                                const unsigned short* __restrict__ h,
                                const float* __restrict__ b, unsigned short* __restrict__ out) {
    int tid = threadIdx.x;
    int wid = tid >> 6, lane = tid & 63;
    int sub = lane >> 4, q = lane & 15;
    int node = blockIdx.x * 4 + wid;
    float dn = dinv[node];
    float4 acc = agg_body(rowptr[node], rowend[node], csr, h, sub, q);
    ushort4 su = *(const ushort4*)&h[node * HID + 4 * q];
    float4 bb = *(const float4*)&b[4 * q];
    float dn2 = dn * dn;
    ushort4 v;
    v.x = f2bf(fmaxf(acc.x + dn2 * bf2f(su.x) + bb.x, 0.0f));
    v.y = f2bf(fmaxf(acc.y + dn2 * bf2f(su.y) + bb.y, 0.0f));
    v.z = f2bf(fmaxf(acc.z + dn2 * bf2f(su.z) + bb.z, 0.0f));
    v.w = f2bf(fmaxf(acc.w + dn2 * bf2f(su.w) + bb.w, 0.0f));
    if (sub == 0) *(ushort4*)&out[node * HID + 4 * q] = v;
}

// ---- gather-aggregate + relu + fused mean-pool (pool stays fp32) ----
__global__ void agg_pool_kernel(const int* __restrict__ rowptr, const int* __restrict__ rowend,
                                const int2* __restrict__ csr, const float* __restrict__ dinv,
                                const unsigned short* __restrict__ h,
                                const float* __restrict__ b, const int* __restrict__ batch,
                                float* __restrict__ pool, float* __restrict__ gcnt) {
    __shared__ float red[4][HID];
    __shared__ int gid[4];
    int tid = threadIdx.x;
    int wid = tid >> 6, lane = tid & 63;
    int sub = lane >> 4, q = lane & 15;
    int node = blockIdx.x * 4 + wid;
    float dn = dinv[node];
    float4 acc = agg_body(rowptr[node], rowend[node], csr, h, sub, q);
    ushort4 su = *(const ushort4*)&h[node * HID + 4 * q];
    float4 bb = *(const float4*)&b[4 * q];
    float dn2 = dn * dn;
    float4 v;
    v.x = fmaxf(acc.x + dn2 * bf2f(su.x) + bb.x, 0.0f);
    v.y = fmaxf(acc.y + dn2 * bf2f(su.y) + bb.y, 0.0f);
    v.z = fmaxf(acc.z + dn2 * bf2f(su.z) + bb.z, 0.0f);
    v.w = fmaxf(acc.w + dn2 * bf2f(su.w) + bb.w, 0.0f);
    if (sub == 0) *(float4*)&red[wid][4 * q] = v;
    if (lane == 0) gid[wid] = batch[node];
    __syncthreads();
    if (wid == 0) {
        int c = lane;
        float r0 = red[0][c], r1 = red[1][c], r2 = red[2][c], r3 = red[3][c];
        int g0 = gid[0], g1 = gid[1], g2 = gid[2], g3 = gid[3];
        if (g0 == g3) {
            atomicAdd(&pool[g0 * HID + c], r0 + r1 + r2 + r3);
            if (c == 0) atomicAdd(&gcnt[g0], 4.0f);
        } else {
            atomicAdd(&pool[g0 * HID + c], r0);
            atomicAdd(&pool[g1 * HID + c], r1);
            atomicAdd(&pool[g2 * HID + c], r2);
            atomicAdd(&pool[g3 * HID + c], r3);
            if (c == 0) {
                atomicAdd(&gcnt[g0], 1.0f);
                atomicAdd(&gcnt[g1], 1.0f);
                atomicAdd(&gcnt[g2], 1.0f);
                atomicAdd(&gcnt[g3], 1.0f);
            }
        }
    }
}

// ---- x @ W1 : [N,12] @ [12,64] -> bf16 ----
__global__ void xw1_kernel(const float* __restrict__ x, const float* __restrict__ W1,
                           unsigned short* __restrict__ h) {
    __shared__ float sW[IN_CH * HID];
    __shared__ float sx[16 * IN_CH];
    int tid = threadIdx.x;
    for (int i = tid; i < IN_CH * HID; i += 256) sW[i] = W1[i];
    int node0 = blockIdx.x * 16;
    if (tid < 16 * IN_CH) sx[tid] = x[node0 * IN_CH + tid];
    __syncthreads();
    int nl = tid >> 4, c4 = (tid & 15) * 4;
    float a0 = 0, a1 = 0, a2 = 0, a3 = 0;
#pragma unroll
    for (int k = 0; k < IN_CH; k++) {
        float xv = sx[nl * IN_CH + k];
        const float* w = &sW[k * HID + c4];
        a0 += xv * w[0]; a1 += xv * w[1]; a2 += xv * w[2]; a3 += xv * w[3];
    }
    ushort4 v = {f2bf(a0), f2bf(a1), f2bf(a2), f2bf(a3)};
    *(ushort4*)&h[(node0 + nl) * HID + c4] = v;
}

// ---- h @ W2 : [N,64] @ [64,64], bf16 in/out, fp32 compute ----
__global__ void hw2_kernel(const unsigned short* __restrict__ hin,
                           const float* __restrict__ W2, unsigned short* __restrict__ hout) {
    __shared__ float sW[HID * HID];
    __shared__ __align__(16) float sh[16 * HID];
    int tid = threadIdx.x;
    for (int i = tid; i < HID * HID; i += 256) sW[i] = W2[i];
    int node0 = blockIdx.x * 16;
    {
        ushort4 u = *(const ushort4*)&hin[node0 * HID + 4 * tid];
        sh[4 * tid + 0] = bf2f(u.x); sh[4 * tid + 1] = bf2f(u.y);
        sh[4 * tid + 2] = bf2f(u.z); sh[4 * tid + 3] = bf2f(u.w);
    }
    __syncthreads();
    int nl = tid >> 4, c4 = (tid & 15) * 4;
    float a0 = 0, a1 = 0, a2 = 0, a3 = 0;
#pragma unroll 8
    for (int k = 0; k < HID; k++) {
        float hv = sh[nl * HID + k];
        float4 w = *(const float4*)&sW[k * HID + c4];
        a0 += hv * w.x; a1 += hv * w.y; a2 += hv * w.z; a3 += hv * w.w;
    }
    ushort4 v = {f2bf(a0), f2bf(a1), f2bf(a2), f2bf(a3)};
    *(ushort4*)&hout[(node0 + nl) * HID + c4] = v;
}

// ---- final: out = sigmoid((pool/cnt) @ Wfc + bfc) ----
__global__ void final_kernel(const float* __restrict__ pool, const float* __restrict__ gcnt,
                             const float* __restrict__ Wfc, const float* __restrict__ bfc,
                             float* __restrict__ out) {
    int idx = blockIdx.x * 256 + threadIdx.x;
    if (idx >= N_GRAPHS * OUT_CH) return;
    int g = idx >> 2, o = idx & 3;
    float inv = 1.0f / fmaxf(gcnt[g], 1.0f);
    float acc = bfc[o];
#pragma unroll
    for (int k = 0; k < HID; k++) acc += pool[g * HID + k] * inv * Wfc[k * OUT_CH + o];
    out[idx] = 1.0f / (1.0f + expf(-acc));
}

extern "C" void kernel_launch(void* const* d_in, const int* in_sizes, int n_in,
                              void* d_out, int out_size, void* d_ws, size_t ws_size,
                              hipStream_t stream) {
    const float* x   = (const float*)d_in[0];
    const int* eidx  = (const int*)d_in[1];
    const int* batch = (const int*)d_in[2];
    const float* W1  = (const float*)d_in[3];
    const float* b1  = (const float*)d_in[4];
    const float* W2  = (const float*)d_in[5];
    const float* b2  = (const float*)d_in[6];
    const float* Wfc = (const float*)d_in[7];
    const float* bfc = (const float*)d_in[8];
    float* out = (float*)d_out;

    const int* src = eidx;
    const int* dst = eidx + N_EDGES;

    // workspace layout (~50 MB)
    unsigned short* hA = (unsigned short*)d_ws;              // 16 MB bf16
    unsigned short* hB = hA + (size_t)N_NODES * HID;         // 16 MB bf16
    int2*  csr    = (int2*)(hB + (size_t)N_NODES * HID);     // 16 MB {src, norm}
    float* dinv   = (float*)(csr + N_EDGES);                 // 512 KB
    int*   cnt    = (int*)(dinv + N_NODES);                  // 512 KB (alias rowptr_work)
    int*   rowptr = cnt + N_NODES;                           // 512 KB
    int*   bsum   = rowptr + N_NODES;                        // 2 KB
    float* pool   = (float*)(bsum + 512);                    // 512 KB
    float* gcnt   = pool + N_GRAPHS * HID;                   // 8 KB
    int*   rowptr_work = cnt;

    hipMemsetAsync(cnt, 0, (size_t)N_NODES * 4, stream);
    hipMemsetAsync(pool, 0, (size_t)(N_GRAPHS * HID + N_GRAPHS) * 4, stream);

    // build CSR (by dst) with per-edge norms
    hist_kernel<<<N_EDGES / 256, 256, 0, stream>>>(dst, cnt);
    scan1_kernel<<<N_NODES / 256, 256, 0, stream>>>(cnt, rowptr, bsum, dinv);
    scan2_kernel<<<1, 512, 0, stream>>>(bsum);
    scan3_kernel<<<N_NODES / 256, 256, 0, stream>>>(rowptr, bsum, rowptr_work);
    // 8 partitions x (N_EDGES/2048) slices
    fill_part_kernel<<<8 * (N_EDGES / 2048), 256, 0, stream>>>(src, dst, dinv, rowptr_work, csr);
    // rowptr_work[d] now equals row END pointer

    // layer 1
    xw1_kernel<<<N_NODES / 16, 256, 0, stream>>>(x, W1, hA);
    agg_relu_kernel<<<N_NODES / 4, 256, 0, stream>>>(rowptr, rowptr_work, csr, dinv, hA, b1, hB);

    // layer 2 (pool fused; h2 never materialized)
    hw2_kernel<<<N_NODES / 16, 256, 0, stream>>>(hB, W2, hA);
    agg_pool_kernel<<<N_NODES / 4, 256, 0, stream>>>(rowptr, rowptr_work, csr, dinv, hA, b2,
                                                     batch, pool, gcnt);

    // head
    final_kernel<<<(N_GRAPHS * OUT_CH + 255) / 256, 256, 0, stream>>>(pool, gcnt, Wfc, bfc, out);
}

// Round 6
// 422.482 us; speedup vs baseline: 1.2365x; 1.0566x over previous
//
#include <hip/hip_runtime.h>
#include <hip/hip_bf16.h>

// GCN via device-built CSR. CSR fill is a 2-pass LDS bucket sort so every
// global write is wave-contiguous (scattered per-lane stores cost a full 64B
// line each on gfx950 TCC — measured R3/R4/R5: 2M x 8B scattered stores ->
// 131MB WRITE_SIZE). Features stored bf16, fp32 accumulate.

#define N_NODES 131072
#define N_EDGES 2097152
#define N_GRAPHS 2048
#define IN_CH 12
#define HID 64
#define OUT_CH 4
#define NBUCK 512          // buckets of 256 dst nodes
#define CHUNK 8192         // edges per bucket_kernel block
#define CAP 5120           // csr_build LDS image capacity (mean 4096, sd 64)

__device__ __forceinline__ unsigned short f2bf(float f) {
    unsigned u = __float_as_uint(f);
    return (unsigned short)((u + 0x7fffu + ((u >> 16) & 1u)) >> 16);  // RNE
}
__device__ __forceinline__ float bf2f(unsigned short b) {
    return __uint_as_float((unsigned)b << 16);
}

// ---- in-degree histogram ----
__global__ void hist_kernel(const int* __restrict__ dst, int* __restrict__ cnt) {
    int e = blockIdx.x * 256 + threadIdx.x;
    atomicAdd(&cnt[dst[e]], 1);
}

// ---- scan phase 1: per-block exclusive scan + block sums; also dinv ----
__global__ void scan1_kernel(const int* __restrict__ cnt, int* __restrict__ rowptr,
                             int* __restrict__ bsum, float* __restrict__ dinv) {
    __shared__ int tmp[256];
    int i = blockIdx.x * 256 + threadIdx.x;
    int v = cnt[i];
    dinv[i] = rsqrtf((float)v + 1.0f);  // +1 self loop
    tmp[threadIdx.x] = v;
    __syncthreads();
    for (int off = 1; off < 256; off <<= 1) {
        int t = (threadIdx.x >= off) ? tmp[threadIdx.x - off] : 0;
        __syncthreads();
        tmp[threadIdx.x] += t;
        __syncthreads();
    }
    rowptr[i] = tmp[threadIdx.x] - v;  // exclusive
    if (threadIdx.x == 255) bsum[blockIdx.x] = tmp[255];
}

// ---- scan phase 2: exclusive scan of 512 block sums ----
__global__ void scan2_kernel(int* __restrict__ bsum) {
    __shared__ int tmp[512];
    int t = threadIdx.x;
    int v = bsum[t];
    tmp[t] = v;
    __syncthreads();
    for (int off = 1; off < 512; off <<= 1) {
        int u = (t >= off) ? tmp[t - off] : 0;
        __syncthreads();
        tmp[t] += u;
        __syncthreads();
    }
    bsum[t] = tmp[t] - v;  // exclusive
}

// ---- scan phase 3: add block offsets; bucket bases; sentinel ----
__global__ void scan3_kernel(int* __restrict__ rowptr, const int* __restrict__ bsum,
                             int* __restrict__ bucket_cursor) {
    int i = blockIdx.x * 256 + threadIdx.x;
    int r = rowptr[i] + bsum[blockIdx.x];
    rowptr[i] = r;
    if ((i & 255) == 0) bucket_cursor[i >> 8] = r;
    if (i == N_NODES - 1) rowptr[N_NODES] = N_EDGES;
}

// ---- pass B: LDS bucket sort of edges by dst>>8; wave-contiguous writes ----
__global__ void bucket_kernel(const int* __restrict__ src, const int* __restrict__ dst,
                              int* __restrict__ bucket_cursor, int* __restrict__ staged) {
    __shared__ int hist[NBUCK];
    __shared__ int lscan[NBUCK];   // inclusive scan of hist
    __shared__ int gbase[NBUCK];
    __shared__ int cursor[NBUCK];
    __shared__ int sorted[CHUNK];  // 32 KB
    int tid = threadIdx.x;
    int base = blockIdx.x * CHUNK;
    for (int b = tid; b < NBUCK; b += 256) { hist[b] = 0; cursor[b] = 0; }
    __syncthreads();
    // count
    for (int i = tid; i < CHUNK; i += 256) atomicAdd(&hist[dst[base + i] >> 8], 1);
    __syncthreads();
    for (int b = tid; b < NBUCK; b += 256) lscan[b] = hist[b];
    __syncthreads();
    // Hillis-Steele inclusive scan over 512 (2 elems/thread)
    for (int off = 1; off < NBUCK; off <<= 1) {
        int i0 = tid, i1 = tid + 256;
        int v0 = (i0 >= off) ? lscan[i0 - off] : 0;
        int v1 = (i1 >= off) ? lscan[i1 - off] : 0;
        __syncthreads();
        lscan[i0] += v0;
        lscan[i1] += v1;
        __syncthreads();
    }
    // reserve global runs
    for (int b = tid; b < NBUCK; b += 256) gbase[b] = atomicAdd(&bucket_cursor[b], hist[b]);
    __syncthreads();
    // place: pack record = (d&255)<<17 | s   (s < 2^17; bucket id implicit)
    for (int i = tid; i < CHUNK; i += 256) {
        int d = dst[base + i];
        int s = src[base + i];
        int b = d >> 8;
        int start = lscan[b] - hist[b];
        int p = start + atomicAdd(&cursor[b], 1);
        sorted[p] = ((d & 255) << 17) | s;
    }
    __syncthreads();
    // flush runs (wave per bucket round-robin; lanes contiguous -> coalesced)
    int wid = tid >> 6, lane = tid & 63;
    for (int b = wid; b < NBUCK; b += 4) {
        int cb = hist[b];
        int lbase = lscan[b] - cb;
        int gb = gbase[b];
        for (int k = lane; k < cb; k += 64) staged[gb + k] = sorted[lbase + k];
    }
}

// ---- pass C: per-bucket fine CSR build in LDS, contiguous flush ----
__global__ void csr_build_kernel(const int* __restrict__ rowptr, const int* __restrict__ staged,
                                 const float* __restrict__ dinv, int2* __restrict__ csr) {
    __shared__ int loff[256];
    __shared__ int cursor[256];
    __shared__ float ldinv[256];
    __shared__ int2 image[CAP];  // 40 KB
    int b = blockIdx.x;
    int tid = threadIdx.x;
    int nbase = b << 8;
    int beg = rowptr[nbase];
    int end = rowptr[nbase + 256];  // sentinel covers last bucket
    int count = end - beg;
    loff[tid] = rowptr[nbase + tid] - beg;
    cursor[tid] = 0;
    ldinv[tid] = dinv[nbase + tid];
    __syncthreads();
    for (int i = tid; i < count; i += 256) {
        int rec = staged[beg + i];
        int s = rec & 0x1FFFF;
        int dq = (rec >> 17) & 255;
        float norm = dinv[s] * ldinv[dq];
        int p = loff[dq] + atomicAdd(&cursor[dq], 1);
        int2 val = make_int2(s, __float_as_int(norm));
        if (p < CAP) image[p] = val;
        else csr[beg + p] = val;  // statistical-impossibility fallback, still correct
    }
    __syncthreads();
    int lim = count < CAP ? count : CAP;
    for (int i = tid; i < lim; i += 256) csr[beg + i] = image[i];
}

// ---- shared gather body over bf16 features; 4 edges/subgroup in flight ----
__device__ __forceinline__ float4 agg_body(int beg, int end, const int2* __restrict__ csr,
                                           const unsigned short* __restrict__ h,
                                           int sub, int q) {
    float4 a0 = {0, 0, 0, 0}, a1 = {0, 0, 0, 0}, a2 = {0, 0, 0, 0}, a3 = {0, 0, 0, 0};
    int j = beg;
    for (; j + 15 < end; j += 16) {
        int2 e0 = csr[j + sub];
        int2 e1 = csr[j + 4 + sub];
        int2 e2 = csr[j + 8 + sub];
        int2 e3 = csr[j + 12 + sub];
        ushort4 u0 = *(const ushort4*)&h[e0.x * HID + 4 * q];
        ushort4 u1 = *(const ushort4*)&h[e1.x * HID + 4 * q];
        ushort4 u2 = *(const ushort4*)&h[e2.x * HID + 4 * q];
        ushort4 u3 = *(const ushort4*)&h[e3.x * HID + 4 * q];
        float n0 = __int_as_float(e0.y), n1 = __int_as_float(e1.y);
        float n2 = __int_as_float(e2.y), n3 = __int_as_float(e3.y);
        a0.x += n0 * bf2f(u0.x); a0.y += n0 * bf2f(u0.y);
        a0.z += n0 * bf2f(u0.z); a0.w += n0 * bf2f(u0.w);
        a1.x += n1 * bf2f(u1.x); a1.y += n1 * bf2f(u1.y);
        a1.z += n1 * bf2f(u1.z); a1.w += n1 * bf2f(u1.w);
        a2.x += n2 * bf2f(u2.x); a2.y += n2 * bf2f(u2.y);
        a2.z += n2 * bf2f(u2.z); a2.w += n2 * bf2f(u2.w);
        a3.x += n3 * bf2f(u3.x); a3.y += n3 * bf2f(u3.y);
        a3.z += n3 * bf2f(u3.z); a3.w += n3 * bf2f(u3.w);
    }
    for (; j + 7 < end; j += 8) {
        int2 e0 = csr[j + sub];
        int2 e1 = csr[j + 4 + sub];
        ushort4 u0 = *(const ushort4*)&h[e0.x * HID + 4 * q];
        ushort4 u1 = *(const ushort4*)&h[e1.x * HID + 4 * q];
        float n0 = __int_as_float(e0.y), n1 = __int_as_float(e1.y);
        a0.x += n0 * bf2f(u0.x); a0.y += n0 * bf2f(u0.y);
        a0.z += n0 * bf2f(u0.z); a0.w += n0 * bf2f(u0.w);
        a1.x += n1 * bf2f(u1.x); a1.y += n1 * bf2f(u1.y);
        a1.z += n1 * bf2f(u1.z); a1.w += n1 * bf2f(u1.w);
    }
    for (; j + sub < end; j += 4) {
        int2 e0 = csr[j + sub];
        ushort4 u0 = *(const ushort4*)&h[e0.x * HID + 4 * q];
        float n0 = __int_as_float(e0.y);
        a0.x += n0 * bf2f(u0.x); a0.y += n0 * bf2f(u0.y);
        a0.z += n0 * bf2f(u0.z); a0.w += n0 * bf2f(u0.w);
    }
    float4 acc;
    acc.x = (a0.x + a1.x) + (a2.x + a3.x);
    acc.y = (a0.y + a1.y) + (a2.y + a3.y);
    acc.z = (a0.z + a1.z) + (a2.z + a3.z);
    acc.w = (a0.w + a1.w) + (a2.w + a3.w);
    acc.x += __shfl_xor(acc.x, 16, 64); acc.y += __shfl_xor(acc.y, 16, 64);
    acc.z += __shfl_xor(acc.z, 16, 64); acc.w += __shfl_xor(acc.w, 16, 64);
    acc.x += __shfl_xor(acc.x, 32, 64); acc.y += __shfl_xor(acc.y, 32, 64);
    acc.z += __shfl_xor(acc.z, 32, 64); acc.w += __shfl_xor(acc.w, 32, 64);
    return acc;
}

// ---- gather-aggregate + self loop + bias + relu -> bf16 out ----
__global__ void agg_relu_kernel(const int* __restrict__ rowptr, const int2* __restrict__ csr,
                                const float* __restrict__ dinv,
                                const unsigned short* __restrict__ h,
                                const float* __restrict__ b, unsigned short* __restrict__ out) {
    int tid = threadIdx.x;
    int wid = tid >> 6, lane = tid & 63;
    int sub = lane >> 4, q = lane & 15;
    int node = blockIdx.x * 4 + wid;
    float dn = dinv[node];
    float4 acc = agg_body(rowptr[node], rowptr[node + 1], csr, h, sub, q);
    ushort4 su = *(const ushort4*)&h[node * HID + 4 * q];
    float4 bb = *(const float4*)&b[4 * q];
    float dn2 = dn * dn;
    ushort4 v;
    v.x = f2bf(fmaxf(acc.x + dn2 * bf2f(su.x) + bb.x, 0.0f));
    v.y = f2bf(fmaxf(acc.y + dn2 * bf2f(su.y) + bb.y, 0.0f));
    v.z = f2bf(fmaxf(acc.z + dn2 * bf2f(su.z) + bb.z, 0.0f));
    v.w = f2bf(fmaxf(acc.w + dn2 * bf2f(su.w) + bb.w, 0.0f));
    if (sub == 0) *(ushort4*)&out[node * HID + 4 * q] = v;
}

// ---- gather-aggregate + relu + fused mean-pool (pool stays fp32) ----
__global__ void agg_pool_kernel(const int* __restrict__ rowptr, const int2* __restrict__ csr,
                                const float* __restrict__ dinv,
                                const unsigned short* __restrict__ h,
                                const float* __restrict__ b, const int* __restrict__ batch,
                                float* __restrict__ pool, float* __restrict__ gcnt) {
    __shared__ float red[4][HID];
    __shared__ int gid[4];
    int tid = threadIdx.x;
    int wid = tid >> 6, lane = tid & 63;
    int sub = lane >> 4, q = lane & 15;
    int node = blockIdx.x * 4 + wid;
    float dn = dinv[node];
    float4 acc = agg_body(rowptr[node], rowptr[node + 1], csr, h, sub, q);
    ushort4 su = *(const ushort4*)&h[node * HID + 4 * q];
    float4 bb = *(const float4*)&b[4 * q];
    float dn2 = dn * dn;
    float4 v;
    v.x = fmaxf(acc.x + dn2 * bf2f(su.x) + bb.x, 0.0f);
    v.y = fmaxf(acc.y + dn2 * bf2f(su.y) + bb.y, 0.0f);
    v.z = fmaxf(acc.z + dn2 * bf2f(su.z) + bb.z, 0.0f);
    v.w = fmaxf(acc.w + dn2 * bf2f(su.w) + bb.w, 0.0f);
    if (sub == 0) *(float4*)&red[wid][4 * q] = v;
    if (lane == 0) gid[wid] = batch[node];
    __syncthreads();
    if (wid == 0) {
        int c = lane;
        float r0 = red[0][c], r1 = red[1][c], r2 = red[2][c], r3 = red[3][c];
        int g0 = gid[0], g1 = gid[1], g2 = gid[2], g3 = gid[3];
        if (g0 == g3) {
            atomicAdd(&pool[g0 * HID + c], r0 + r1 + r2 + r3);
            if (c == 0) atomicAdd(&gcnt[g0], 4.0f);
        } else {
            atomicAdd(&pool[g0 * HID + c], r0);
            atomicAdd(&pool[g1 * HID + c], r1);
            atomicAdd(&pool[g2 * HID + c], r2);
            atomicAdd(&pool[g3 * HID + c], r3);
            if (c == 0) {
                atomicAdd(&gcnt[g0], 1.0f);
                atomicAdd(&gcnt[g1], 1.0f);
                atomicAdd(&gcnt[g2], 1.0f);
                atomicAdd(&gcnt[g3], 1.0f);
            }
        }
    }
}

// ---- x @ W1 : [N,12] @ [12,64] -> bf16 ----
__global__ void xw1_kernel(const float* __restrict__ x, const float* __restrict__ W1,
                           unsigned short* __restrict__ h) {
    __shared__ float sW[IN_CH * HID];
    __shared__ float sx[16 * IN_CH];
    int tid = threadIdx.x;
    for (int i = tid; i < IN_CH * HID; i += 256) sW[i] = W1[i];
    int node0 = blockIdx.x * 16;
    if (tid < 16 * IN_CH) sx[tid] = x[node0 * IN_CH + tid];
    __syncthreads();
    int nl = tid >> 4, c4 = (tid & 15) * 4;
    float a0 = 0, a1 = 0, a2 = 0, a3 = 0;
#pragma unroll
    for (int k = 0; k < IN_CH; k++) {
        float xv = sx[nl * IN_CH + k];
        const float* w = &sW[k * HID + c4];
        a0 += xv * w[0]; a1 += xv * w[1]; a2 += xv * w[2]; a3 += xv * w[3];
    }
    ushort4 v = {f2bf(a0), f2bf(a1), f2bf(a2), f2bf(a3)};
    *(ushort4*)&h[(node0 + nl) * HID + c4] = v;
}

// ---- h @ W2 : [N,64] @ [64,64], bf16 in/out, fp32 compute ----
__global__ void hw2_kernel(const unsigned short* __restrict__ hin,
                           const float* __restrict__ W2, unsigned short* __restrict__ hout) {
    __shared__ float sW[HID * HID];
    __shared__ __align__(16) float sh[16 * HID];
    int tid = threadIdx.x;
    for (int i = tid; i < HID * HID; i += 256) sW[i] = W2[i];
    int node0 = blockIdx.x * 16;
    {
        ushort4 u = *(const ushort4*)&hin[node0 * HID + 4 * tid];
        sh[4 * tid + 0] = bf2f(u.x); sh[4 * tid + 1] = bf2f(u.y);
        sh[4 * tid + 2] = bf2f(u.z); sh[4 * tid + 3] = bf2f(u.w);
    }
    __syncthreads();
    int nl = tid >> 4, c4 = (tid & 15) * 4;
    float a0 = 0, a1 = 0, a2 = 0, a3 = 0;
#pragma unroll 8
    for (int k = 0; k < HID; k++) {
        float hv = sh[nl * HID + k];
        float4 w = *(const float4*)&sW[k * HID + c4];
        a0 += hv * w.x; a1 += hv * w.y; a2 += hv * w.z; a3 += hv * w.w;
    }
    ushort4 v = {f2bf(a0), f2bf(a1), f2bf(a2), f2bf(a3)};
    *(ushort4*)&hout[(node0 + nl) * HID + c4] = v;
}

// ---- final: out = sigmoid((pool/cnt) @ Wfc + bfc) ----
__global__ void final_kernel(const float* __restrict__ pool, const float* __restrict__ gcnt,
                             const float* __restrict__ Wfc, const float* __restrict__ bfc,
                             float* __restrict__ out) {
    int idx = blockIdx.x * 256 + threadIdx.x;
    if (idx >= N_GRAPHS * OUT_CH) return;
    int g = idx >> 2, o = idx & 3;
    float inv = 1.0f / fmaxf(gcnt[g], 1.0f);
    float acc = bfc[o];
#pragma unroll
    for (int k = 0; k < HID; k++) acc += pool[g * HID + k] * inv * Wfc[k * OUT_CH + o];
    out[idx] = 1.0f / (1.0f + expf(-acc));
}

extern "C" void kernel_launch(void* const* d_in, const int* in_sizes, int n_in,
                              void* d_out, int out_size, void* d_ws, size_t ws_size,
                              hipStream_t stream) {
    const float* x   = (const float*)d_in[0];
    const int* eidx  = (const int*)d_in[1];
    const int* batch = (const int*)d_in[2];
    const float* W1  = (const float*)d_in[3];
    const float* b1  = (const float*)d_in[4];
    const float* W2  = (const float*)d_in[5];
    const float* b2  = (const float*)d_in[6];
    const float* Wfc = (const float*)d_in[7];
    const float* bfc = (const float*)d_in[8];
    float* out = (float*)d_out;

    const int* src = eidx;
    const int* dst = eidx + N_EDGES;

    // workspace layout (~58 MB)
    unsigned short* hA = (unsigned short*)d_ws;              // 16 MB bf16
    unsigned short* hB = hA + (size_t)N_NODES * HID;         // 16 MB bf16
    int2*  csr    = (int2*)(hB + (size_t)N_NODES * HID);     // 16 MB {src, norm}
    int*   staged = (int*)(csr + N_EDGES);                   // 8 MB packed records
    float* dinv   = (float*)(staged + N_EDGES);              // 512 KB
    int*   cnt    = (int*)(dinv + N_NODES);                  // 512 KB
    int*   rowptr = cnt + N_NODES;                           // 512 KB + sentinel
    int*   bsum   = rowptr + N_NODES + 1;                    // 2 KB
    int*   bucket_cursor = bsum + 512;                       // 2 KB
    float* pool   = (float*)(bucket_cursor + NBUCK);         // 512 KB
    float* gcnt   = pool + N_GRAPHS * HID;                   // 8 KB

    hipMemsetAsync(cnt, 0, (size_t)N_NODES * 4, stream);
    hipMemsetAsync(pool, 0, (size_t)(N_GRAPHS * HID + N_GRAPHS) * 4, stream);

    // degree + rowptr + bucket bases
    hist_kernel<<<N_EDGES / 256, 256, 0, stream>>>(dst, cnt);
    scan1_kernel<<<N_NODES / 256, 256, 0, stream>>>(cnt, rowptr, bsum, dinv);
    scan2_kernel<<<1, 512, 0, stream>>>(bsum);
    scan3_kernel<<<N_NODES / 256, 256, 0, stream>>>(rowptr, bsum, bucket_cursor);

    // 2-pass bucket sort -> ordered CSR with precomputed norms
    bucket_kernel<<<N_EDGES / CHUNK, 256, 0, stream>>>(src, dst, bucket_cursor, staged);
    csr_build_kernel<<<NBUCK, 256, 0, stream>>>(rowptr, staged, dinv, csr);

    // layer 1
    xw1_kernel<<<N_NODES / 16, 256, 0, stream>>>(x, W1, hA);
    agg_relu_kernel<<<N_NODES / 4, 256, 0, stream>>>(rowptr, csr, dinv, hA, b1, hB);

    // layer 2 (pool fused; h2 never materialized)
    hw2_kernel<<<N_NODES / 16, 256, 0, stream>>>(hB, W2, hA);
    agg_pool_kernel<<<N_NODES / 4, 256, 0, stream>>>(rowptr, csr, dinv, hA, b2, batch,
                                                     pool, gcnt);

    // head
    final_kernel<<<(N_GRAPHS * OUT_CH + 255) / 256, 256, 0, stream>>>(pool, gcnt, Wfc, bfc, out);
}

// Round 7
// 339.024 us; speedup vs baseline: 1.5409x; 1.2462x over previous
//
#include <hip/hip_runtime.h>
#include <hip/hip_bf16.h>

// GCN. CSR built by 2-pass LDS bucket sort (all global writes wave-contiguous;
// scattered 8B stores cost a full 64B line each on gfx950 TCC — measured R3-R5).
// No global fine histogram: per-bucket degree/rowptr/dinv derived in LDS from
// staged records. Features bf16 (fp32 accumulate). Agg: 8 edges/wave-instr,
// 16 in flight, lane = 8 channels (uint4).

#define N_NODES 131072
#define N_EDGES 2097152
#define N_GRAPHS 2048
#define IN_CH 12
#define HID 64
#define OUT_CH 4
#define NBUCK 512          // buckets of 256 dst nodes
#define CHUNK 8192         // edges per bucket_kernel block
#define STRIDE 4608        // staging capacity per bucket (mean 4096, sd 64)
#define CAP 5120           // place_kernel LDS image capacity

__device__ __forceinline__ unsigned short f2bf(float f) {
    unsigned u = __float_as_uint(f);
    return (unsigned short)((u + 0x7fffu + ((u >> 16) & 1u)) >> 16);  // RNE
}
__device__ __forceinline__ unsigned pack2bf(float lo, float hi) {
    return (unsigned)f2bf(lo) | ((unsigned)f2bf(hi) << 16);
}
__device__ __forceinline__ float bflo(unsigned v) { return __uint_as_float(v << 16); }
__device__ __forceinline__ float bfhi(unsigned v) { return __uint_as_float(v & 0xFFFF0000u); }

// ---- pass A: LDS bucket sort of edges by dst>>8 into strided staging ----
__global__ void bucket_kernel(const int* __restrict__ src, const int* __restrict__ dst,
                              int* __restrict__ bucket_count, int* __restrict__ staged) {
    __shared__ int hist[NBUCK];
    __shared__ int lscan[NBUCK];
    __shared__ int gbase[NBUCK];
    __shared__ int cursor[NBUCK];
    __shared__ int sorted[CHUNK];  // 32 KB
    int tid = threadIdx.x;
    int base = blockIdx.x * CHUNK;
    for (int b = tid; b < NBUCK; b += 256) { hist[b] = 0; cursor[b] = 0; }
    __syncthreads();
    for (int i = tid; i < CHUNK; i += 256) atomicAdd(&hist[dst[base + i] >> 8], 1);
    __syncthreads();
    for (int b = tid; b < NBUCK; b += 256) lscan[b] = hist[b];
    __syncthreads();
    for (int off = 1; off < NBUCK; off <<= 1) {
        int i0 = tid, i1 = tid + 256;
        int v0 = (i0 >= off) ? lscan[i0 - off] : 0;
        int v1 = (i1 >= off) ? lscan[i1 - off] : 0;
        __syncthreads();
        lscan[i0] += v0;
        lscan[i1] += v1;
        __syncthreads();
    }
    for (int b = tid; b < NBUCK; b += 256) gbase[b] = atomicAdd(&bucket_count[b], hist[b]);
    __syncthreads();
    // pack record = (d&255)<<17 | s   (s < 2^17)
    for (int i = tid; i < CHUNK; i += 256) {
        int d = dst[base + i];
        int s = src[base + i];
        int b = d >> 8;
        int start = lscan[b] - hist[b];
        int p = start + atomicAdd(&cursor[b], 1);
        sorted[p] = ((d & 255) << 17) | s;
    }
    __syncthreads();
    int wid = tid >> 6, lane = tid & 63;
    for (int b = wid; b < NBUCK; b += 4) {
        int cb = hist[b];
        int lbase = lscan[b] - cb;
        int gb = b * STRIDE + gbase[b];
        for (int k = lane; k < cb; k += 64) staged[gb + k] = sorted[lbase + k];
    }
}

// ---- scan of 512 bucket counts -> exclusive bases (+ total sentinel) ----
__global__ void scan2_kernel(const int* __restrict__ bucket_count, int* __restrict__ bucket_base) {
    __shared__ int tmp[NBUCK];
    int t = threadIdx.x;
    int v = bucket_count[t];
    tmp[t] = v;
    __syncthreads();
    for (int off = 1; off < NBUCK; off <<= 1) {
        int u = (t >= off) ? tmp[t - off] : 0;
        __syncthreads();
        tmp[t] += u;
        __syncthreads();
    }
    bucket_base[t] = tmp[t] - v;  // exclusive
    if (t == NBUCK - 1) bucket_base[NBUCK] = tmp[t];
}

// ---- per-bucket: fine degree count in LDS -> rowptr, dinv ----
__global__ void count_kernel(const int* __restrict__ bucket_base, const int* __restrict__ staged,
                             int* __restrict__ rowptr, float* __restrict__ dinv) {
    __shared__ int cnt[256];
    __shared__ int scn[256];
    int b = blockIdx.x;
    int tid = threadIdx.x;
    int beg = bucket_base[b];
    int count = bucket_base[b + 1] - beg;
    cnt[tid] = 0;
    __syncthreads();
    const int* st = staged + b * STRIDE;
    for (int i = tid; i < count; i += 256) atomicAdd(&cnt[(st[i] >> 17) & 255], 1);
    __syncthreads();
    int deg = cnt[tid];
    scn[tid] = deg;
    __syncthreads();
    for (int off = 1; off < 256; off <<= 1) {
        int u = (tid >= off) ? scn[tid - off] : 0;
        __syncthreads();
        scn[tid] += u;
        __syncthreads();
    }
    int nbase = b << 8;
    rowptr[nbase + tid] = beg + scn[tid] - deg;  // exclusive
    dinv[nbase + tid] = rsqrtf((float)deg + 1.0f);
    if (b == NBUCK - 1 && tid == 255) rowptr[N_NODES] = N_EDGES;
}

// ---- per-bucket: place records into ordered CSR (LDS image, contiguous flush) ----
__global__ void place_kernel(const int* __restrict__ bucket_base, const int* __restrict__ staged,
                             const int* __restrict__ rowptr, const float* __restrict__ dinv,
                             int2* __restrict__ csr) {
    __shared__ int loff[256];
    __shared__ int cursor[256];
    __shared__ float ldinv[256];
    __shared__ int2 image[CAP];  // 40 KB
    int b = blockIdx.x;
    int tid = threadIdx.x;
    int nbase = b << 8;
    int beg = bucket_base[b];
    int count = bucket_base[b + 1] - beg;
    loff[tid] = rowptr[nbase + tid] - beg;
    cursor[tid] = 0;
    ldinv[tid] = dinv[nbase + tid];
    __syncthreads();
    const int* st = staged + b * STRIDE;
    for (int i = tid; i < count; i += 256) {
        int rec = st[i];
        int s = rec & 0x1FFFF;
        int dq = (rec >> 17) & 255;
        float norm = dinv[s] * ldinv[dq];  // dinv is 512 KB -> L2-resident
        int p = loff[dq] + atomicAdd(&cursor[dq], 1);
        int2 val = make_int2(s, __float_as_int(norm));
        if (p < CAP) image[p] = val;
        else csr[beg + p] = val;  // statistically impossible fallback
    }
    __syncthreads();
    int lim = count < CAP ? count : CAP;
    for (int i = tid; i < lim; i += 256) csr[beg + i] = image[i];
}

// ---- gather body: 8 subgroups x 8 lanes; lane = 8 channels (uint4 of bf16) ----
// Returns 8 fp32 channel sums in r[0..7] (all lanes hold full sum after xor-reduce).
__device__ __forceinline__ void agg_body(int beg, int end, const int2* __restrict__ csr,
                                         const unsigned short* __restrict__ h,
                                         int sub, int q, float* r) {
    float a[8] = {0, 0, 0, 0, 0, 0, 0, 0};
    float c[8] = {0, 0, 0, 0, 0, 0, 0, 0};
    int j = beg;
    for (; j + 15 < end; j += 16) {
        int2 e0 = csr[j + sub];
        int2 e1 = csr[j + 8 + sub];
        uint4 u0 = *(const uint4*)(h + e0.x * HID + 8 * q);
        uint4 u1 = *(const uint4*)(h + e1.x * HID + 8 * q);
        float n0 = __int_as_float(e0.y), n1 = __int_as_float(e1.y);
        a[0] += n0 * bflo(u0.x); a[1] += n0 * bfhi(u0.x);
        a[2] += n0 * bflo(u0.y); a[3] += n0 * bfhi(u0.y);
        a[4] += n0 * bflo(u0.z); a[5] += n0 * bfhi(u0.z);
        a[6] += n0 * bflo(u0.w); a[7] += n0 * bfhi(u0.w);
        c[0] += n1 * bflo(u1.x); c[1] += n1 * bfhi(u1.x);
        c[2] += n1 * bflo(u1.y); c[3] += n1 * bfhi(u1.y);
        c[4] += n1 * bflo(u1.z); c[5] += n1 * bfhi(u1.z);
        c[6] += n1 * bflo(u1.w); c[7] += n1 * bfhi(u1.w);
    }
    for (; j + sub < end; j += 8) {
        int2 e0 = csr[j + sub];
        uint4 u0 = *(const uint4*)(h + e0.x * HID + 8 * q);
        float n0 = __int_as_float(e0.y);
        a[0] += n0 * bflo(u0.x); a[1] += n0 * bfhi(u0.x);
        a[2] += n0 * bflo(u0.y); a[3] += n0 * bfhi(u0.y);
        a[4] += n0 * bflo(u0.z); a[5] += n0 * bfhi(u0.z);
        a[6] += n0 * bflo(u0.w); a[7] += n0 * bfhi(u0.w);
    }
#pragma unroll
    for (int k = 0; k < 8; k++) {
        float v = a[k] + c[k];
        v += __shfl_xor(v, 8, 64);
        v += __shfl_xor(v, 16, 64);
        v += __shfl_xor(v, 32, 64);
        r[k] = v;
    }
}

// ---- gather-aggregate + self loop + bias + relu -> bf16 out ----
__global__ void agg_relu_kernel(const int* __restrict__ rowptr, const int2* __restrict__ csr,
                                const float* __restrict__ dinv,
                                const unsigned short* __restrict__ h,
                                const float* __restrict__ b, unsigned short* __restrict__ out) {
    int tid = threadIdx.x;
    int wid = tid >> 6, lane = tid & 63;
    int sub = lane >> 3, q = lane & 7;
    int node = blockIdx.x * 4 + wid;
    float dn = dinv[node];
    float r[8];
    agg_body(rowptr[node], rowptr[node + 1], csr, h, sub, q, r);
    if (sub == 0) {
        uint4 su = *(const uint4*)(h + node * HID + 8 * q);
        float4 b0 = *(const float4*)&b[8 * q];
        float4 b1 = *(const float4*)&b[8 * q + 4];
        float dn2 = dn * dn;
        float v0 = fmaxf(r[0] + dn2 * bflo(su.x) + b0.x, 0.0f);
        float v1 = fmaxf(r[1] + dn2 * bfhi(su.x) + b0.y, 0.0f);
        float v2 = fmaxf(r[2] + dn2 * bflo(su.y) + b0.z, 0.0f);
        float v3 = fmaxf(r[3] + dn2 * bfhi(su.y) + b0.w, 0.0f);
        float v4 = fmaxf(r[4] + dn2 * bflo(su.z) + b1.x, 0.0f);
        float v5 = fmaxf(r[5] + dn2 * bfhi(su.z) + b1.y, 0.0f);
        float v6 = fmaxf(r[6] + dn2 * bflo(su.w) + b1.z, 0.0f);
        float v7 = fmaxf(r[7] + dn2 * bfhi(su.w) + b1.w, 0.0f);
        uint4 o;
        o.x = pack2bf(v0, v1); o.y = pack2bf(v2, v3);
        o.z = pack2bf(v4, v5); o.w = pack2bf(v6, v7);
        *(uint4*)(out + node * HID + 8 * q) = o;
    }
}

// ---- gather-aggregate + relu + fused mean-pool (pool fp32) ----
__global__ void agg_pool_kernel(const int* __restrict__ rowptr, const int2* __restrict__ csr,
                                const float* __restrict__ dinv,
                                const unsigned short* __restrict__ h,
                                const float* __restrict__ b, const int* __restrict__ batch,
                                float* __restrict__ pool, float* __restrict__ gcnt) {
    __shared__ float red[4][HID];
    __shared__ int gid[4];
    int tid = threadIdx.x;
    int wid = tid >> 6, lane = tid & 63;
    int sub = lane >> 3, q = lane & 7;
    int node = blockIdx.x * 4 + wid;
    float dn = dinv[node];
    float r[8];
    agg_body(rowptr[node], rowptr[node + 1], csr, h, sub, q, r);
    if (sub == 0) {
        uint4 su = *(const uint4*)(h + node * HID + 8 * q);
        float4 b0 = *(const float4*)&b[8 * q];
        float4 b1 = *(const float4*)&b[8 * q + 4];
        float dn2 = dn * dn;
        float4 v0, v1;
        v0.x = fmaxf(r[0] + dn2 * bflo(su.x) + b0.x, 0.0f);
        v0.y = fmaxf(r[1] + dn2 * bfhi(su.x) + b0.y, 0.0f);
        v0.z = fmaxf(r[2] + dn2 * bflo(su.y) + b0.z, 0.0f);
        v0.w = fmaxf(r[3] + dn2 * bfhi(su.y) + b0.w, 0.0f);
        v1.x = fmaxf(r[4] + dn2 * bflo(su.z) + b1.x, 0.0f);
        v1.y = fmaxf(r[5] + dn2 * bfhi(su.z) + b1.y, 0.0f);
        v1.z = fmaxf(r[6] + dn2 * bflo(su.w) + b1.z, 0.0f);
        v1.w = fmaxf(r[7] + dn2 * bfhi(su.w) + b1.w, 0.0f);
        *(float4*)&red[wid][8 * q] = v0;
        *(float4*)&red[wid][8 * q + 4] = v1;
    }
    if (lane == 0) gid[wid] = batch[node];
    __syncthreads();
    if (wid == 0) {
        int c = lane;
        float r0 = red[0][c], r1 = red[1][c], r2 = red[2][c], r3 = red[3][c];
        int g0 = gid[0], g1 = gid[1], g2 = gid[2], g3 = gid[3];
        if (g0 == g3) {
            atomicAdd(&pool[g0 * HID + c], r0 + r1 + r2 + r3);
            if (c == 0) atomicAdd(&gcnt[g0], 4.0f);
        } else {
            atomicAdd(&pool[g0 * HID + c], r0);
            atomicAdd(&pool[g1 * HID + c], r1);
            atomicAdd(&pool[g2 * HID + c], r2);
            atomicAdd(&pool[g3 * HID + c], r3);
            if (c == 0) {
                atomicAdd(&gcnt[g0], 1.0f);
                atomicAdd(&gcnt[g1], 1.0f);
                atomicAdd(&gcnt[g2], 1.0f);
                atomicAdd(&gcnt[g3], 1.0f);
            }
        }
    }
}

// ---- x @ W1 : [N,12] @ [12,64] -> bf16 ----
__global__ void xw1_kernel(const float* __restrict__ x, const float* __restrict__ W1,
                           unsigned short* __restrict__ h) {
    __shared__ float sW[IN_CH * HID];
    __shared__ float sx[16 * IN_CH];
    int tid = threadIdx.x;
    for (int i = tid; i < IN_CH * HID; i += 256) sW[i] = W1[i];
    int node0 = blockIdx.x * 16;
    if (tid < 16 * IN_CH) sx[tid] = x[node0 * IN_CH + tid];
    __syncthreads();
    int nl = tid >> 4, c4 = (tid & 15) * 4;
    float a0 = 0, a1 = 0, a2 = 0, a3 = 0;
#pragma unroll
    for (int k = 0; k < IN_CH; k++) {
        float xv = sx[nl * IN_CH + k];
        const float* w = &sW[k * HID + c4];
        a0 += xv * w[0]; a1 += xv * w[1]; a2 += xv * w[2]; a3 += xv * w[3];
    }
    ushort4 v = {f2bf(a0), f2bf(a1), f2bf(a2), f2bf(a3)};
    *(ushort4*)&h[(node0 + nl) * HID + c4] = v;
}

// ---- h @ W2 : [N,64] @ [64,64], bf16 in/out, fp32 compute ----
__global__ void hw2_kernel(const unsigned short* __restrict__ hin,
                           const float* __restrict__ W2, unsigned short* __restrict__ hout) {
    __shared__ float sW[HID * HID];
    __shared__ __align__(16) float sh[16 * HID];
    int tid = threadIdx.x;
    for (int i = tid; i < HID * HID; i += 256) sW[i] = W2[i];
    int node0 = blockIdx.x * 16;
    {
        uint2 u = *(const uint2*)&hin[node0 * HID + 4 * tid];
        sh[4 * tid + 0] = bflo(u.x); sh[4 * tid + 1] = bfhi(u.x);
        sh[4 * tid + 2] = bflo(u.y); sh[4 * tid + 3] = bfhi(u.y);
    }
    __syncthreads();
    int nl = tid >> 4, c4 = (tid & 15) * 4;
    float a0 = 0, a1 = 0, a2 = 0, a3 = 0;
#pragma unroll 8
    for (int k = 0; k < HID; k++) {
        float hv = sh[nl * HID + k];
        float4 w = *(const float4*)&sW[k * HID + c4];
        a0 += hv * w.x; a1 += hv * w.y; a2 += hv * w.z; a3 += hv * w.w;
    }
    ushort4 v = {f2bf(a0), f2bf(a1), f2bf(a2), f2bf(a3)};
    *(ushort4*)&hout[(node0 + nl) * HID + c4] = v;
}

// ---- final: out = sigmoid((pool/cnt) @ Wfc + bfc) ----
__global__ void final_kernel(const float* __restrict__ pool, const float* __restrict__ gcnt,
                             const float* __restrict__ Wfc, const float* __restrict__ bfc,
                             float* __restrict__ out) {
    int idx = blockIdx.x * 256 + threadIdx.x;
    if (idx >= N_GRAPHS * OUT_CH) return;
    int g = idx >> 2, o = idx & 3;
    float inv = 1.0f / fmaxf(gcnt[g], 1.0f);
    float acc = bfc[o];
#pragma unroll
    for (int k = 0; k < HID; k++) acc += pool[g * HID + k] * inv * Wfc[k * OUT_CH + o];
    out[idx] = 1.0f / (1.0f + expf(-acc));
}

extern "C" void kernel_launch(void* const* d_in, const int* in_sizes, int n_in,
                              void* d_out, int out_size, void* d_ws, size_t ws_size,
                              hipStream_t stream) {
    const float* x   = (const float*)d_in[0];
    const int* eidx  = (const int*)d_in[1];
    const int* batch = (const int*)d_in[2];
    const float* W1  = (const float*)d_in[3];
    const float* b1  = (const float*)d_in[4];
    const float* W2  = (const float*)d_in[5];
    const float* b2  = (const float*)d_in[6];
    const float* Wfc = (const float*)d_in[7];
    const float* bfc = (const float*)d_in[8];
    float* out = (float*)d_out;

    const int* src = eidx;
    const int* dst = eidx + N_EDGES;

    // workspace layout (~60 MB)
    unsigned short* hA = (unsigned short*)d_ws;              // 16 MB bf16
    unsigned short* hB = hA + (size_t)N_NODES * HID;         // 16 MB bf16
    int2*  csr    = (int2*)(hB + (size_t)N_NODES * HID);     // 16 MB {src, norm}
    int*   staged = (int*)(csr + N_EDGES);                   // 9.4 MB bucket-strided
    float* dinv   = (float*)(staged + (size_t)NBUCK * STRIDE); // 512 KB
    int*   rowptr = (int*)(dinv + N_NODES);                  // 512 KB + sentinel
    int*   bucket_count = rowptr + N_NODES + 1;              // 2 KB
    int*   bucket_base  = bucket_count + NBUCK;              // 2 KB + sentinel
    float* pool   = (float*)(bucket_base + NBUCK + 1);       // 512 KB
    float* gcnt   = pool + N_GRAPHS * HID;                   // 8 KB

    hipMemsetAsync(bucket_count, 0, (size_t)NBUCK * 4, stream);
    hipMemsetAsync(pool, 0, (size_t)(N_GRAPHS * HID + N_GRAPHS) * 4, stream);

    // CSR build: bucket sort -> bases -> degrees/rowptr/dinv -> ordered fill
    bucket_kernel<<<N_EDGES / CHUNK, 256, 0, stream>>>(src, dst, bucket_count, staged);
    scan2_kernel<<<1, NBUCK, 0, stream>>>(bucket_count, bucket_base);
    count_kernel<<<NBUCK, 256, 0, stream>>>(bucket_base, staged, rowptr, dinv);
    place_kernel<<<NBUCK, 256, 0, stream>>>(bucket_base, staged, rowptr, dinv, csr);

    // layer 1
    xw1_kernel<<<N_NODES / 16, 256, 0, stream>>>(x, W1, hA);
    agg_relu_kernel<<<N_NODES / 4, 256, 0, stream>>>(rowptr, csr, dinv, hA, b1, hB);

    // layer 2 (pool fused; h2 never materialized)
    hw2_kernel<<<N_NODES / 16, 256, 0, stream>>>(hB, W2, hA);
    agg_pool_kernel<<<N_NODES / 4, 256, 0, stream>>>(rowptr, csr, dinv, hA, b2, batch,
                                                     pool, gcnt);

    // head
    final_kernel<<<(N_GRAPHS * OUT_CH + 255) / 256, 256, 0, stream>>>(pool, gcnt, Wfc, bfc, out);
}

// Round 8
// 323.335 us; speedup vs baseline: 1.6157x; 1.0485x over previous
//
#include <hip/hip_runtime.h>
#include <hip/hip_bf16.h>

// GCN. CSR built by 2-pass LDS bucket sort (all global writes wave-contiguous;
// scattered 8B stores cost a full 64B line each on gfx950 TCC — measured R3-R5).
// Rows padded to x8 with null edges (src=0,norm=0) -> uniform full-width gather
// chunks, no remainder divergence. Fixed per-bucket CSR stride + rowbounds{beg,end}
// kills the cross-bucket scan. Features bf16 (fp32/f32x2 accumulate).

#define N_NODES 131072
#define N_EDGES 2097152
#define N_GRAPHS 2048
#define IN_CH 12
#define HID 64
#define OUT_CH 4
#define NBUCK 512          // buckets of 256 dst nodes
#define CHUNK 8192         // edges per bucket_kernel block
#define STRIDE 4608        // staging capacity per bucket (mean 4096, sd 64)
#define CSR_STRIDE 5632    // csr capacity per bucket (padded mean 4992, sd ~74)
#define CAP 5632           // place_kernel LDS image capacity (44 KB)

typedef float f32x2 __attribute__((ext_vector_type(2)));

__device__ __forceinline__ unsigned short f2bf(float f) {
    unsigned u = __float_as_uint(f);
    return (unsigned short)((u + 0x7fffu + ((u >> 16) & 1u)) >> 16);  // RNE
}
__device__ __forceinline__ unsigned pack2bf(float lo, float hi) {
    return (unsigned)f2bf(lo) | ((unsigned)f2bf(hi) << 16);
}
__device__ __forceinline__ float bflo(unsigned v) { return __uint_as_float(v << 16); }
__device__ __forceinline__ float bfhi(unsigned v) { return __uint_as_float(v & 0xFFFF0000u); }

// ---- pass A: LDS bucket sort of edges by dst>>8 into strided staging ----
__global__ void bucket_kernel(const int* __restrict__ src, const int* __restrict__ dst,
                              int* __restrict__ bucket_count, int* __restrict__ staged) {
    __shared__ int hist[NBUCK];
    __shared__ int lscan[NBUCK];
    __shared__ int gbase[NBUCK];
    __shared__ int cursor[NBUCK];
    __shared__ int sorted[CHUNK];  // 32 KB
    int tid = threadIdx.x;
    int base = blockIdx.x * CHUNK;
    for (int b = tid; b < NBUCK; b += 256) { hist[b] = 0; cursor[b] = 0; }
    __syncthreads();
    for (int i = tid; i < CHUNK; i += 256) atomicAdd(&hist[dst[base + i] >> 8], 1);
    __syncthreads();
    for (int b = tid; b < NBUCK; b += 256) lscan[b] = hist[b];
    __syncthreads();
    for (int off = 1; off < NBUCK; off <<= 1) {
        int i0 = tid, i1 = tid + 256;
        int v0 = (i0 >= off) ? lscan[i0 - off] : 0;
        int v1 = (i1 >= off) ? lscan[i1 - off] : 0;
        __syncthreads();
        lscan[i0] += v0;
        lscan[i1] += v1;
        __syncthreads();
    }
    for (int b = tid; b < NBUCK; b += 256) gbase[b] = atomicAdd(&bucket_count[b], hist[b]);
    __syncthreads();
    // pack record = (d&255)<<17 | s   (s < 2^17)
    for (int i = tid; i < CHUNK; i += 256) {
        int d = dst[base + i];
        int s = src[base + i];
        int b = d >> 8;
        int start = lscan[b] - hist[b];
        int p = start + atomicAdd(&cursor[b], 1);
        sorted[p] = ((d & 255) << 17) | s;
    }
    __syncthreads();
    int wid = tid >> 6, lane = tid & 63;
    for (int b = wid; b < NBUCK; b += 4) {
        int cb = hist[b];
        int lbase = lscan[b] - cb;
        int gb = b * STRIDE + gbase[b];
        for (int k = lane; k < cb; k += 64) staged[gb + k] = sorted[lbase + k];
    }
}

// ---- per-bucket: fine degree count in LDS -> padded rowbounds, dinv ----
__global__ void count_kernel(const int* __restrict__ bucket_count, const int* __restrict__ staged,
                             int2* __restrict__ rowbounds, float* __restrict__ dinv) {
    __shared__ int cnt[256];
    __shared__ int scn[256];
    int b = blockIdx.x;
    int tid = threadIdx.x;
    int count = bucket_count[b];
    const int* st = staged + b * STRIDE;
    cnt[tid] = 0;
    __syncthreads();
    for (int i = tid; i < count; i += 256) atomicAdd(&cnt[(st[i] >> 17) & 255], 1);
    __syncthreads();
    int deg = cnt[tid];
    int degp = (deg + 7) & ~7;  // pad to x8
    scn[tid] = degp;
    __syncthreads();
    for (int off = 1; off < 256; off <<= 1) {
        int u = (tid >= off) ? scn[tid - off] : 0;
        __syncthreads();
        scn[tid] += u;
        __syncthreads();
    }
    int nbase = (b << 8) + tid;
    int gbeg = b * CSR_STRIDE + scn[tid] - degp;
    rowbounds[nbase] = make_int2(gbeg, gbeg + degp);
    dinv[nbase] = rsqrtf((float)deg + 1.0f);
}

// ---- per-bucket: place records (+zero pads) into CSR via LDS image ----
__global__ void place_kernel(const int* __restrict__ bucket_count, const int* __restrict__ staged,
                             const int2* __restrict__ rowbounds, const float* __restrict__ dinv,
                             int2* __restrict__ csr) {
    __shared__ int loff[256];
    __shared__ int cursor[256];
    __shared__ float ldinv[256];
    __shared__ int totalS;
    __shared__ int2 image[CAP];  // 44 KB
    int b = blockIdx.x;
    int tid = threadIdx.x;
    int nbase = (b << 8) + tid;
    int gb = b * CSR_STRIDE;
    int count = bucket_count[b];
    int2 rb = rowbounds[nbase];
    int lo = rb.x - gb;
    int degp = rb.y - rb.x;
    loff[tid] = lo;
    cursor[tid] = 0;
    ldinv[tid] = dinv[nbase];
    if (tid == 255) totalS = lo + degp;
    __syncthreads();
    const int* st = staged + b * STRIDE;
    for (int i = tid; i < count; i += 256) {
        int rec = st[i];
        int s = rec & 0x1FFFF;
        int dq = (rec >> 17) & 255;
        float norm = dinv[s] * ldinv[dq];  // dinv 512 KB -> L2-resident
        int p = loff[dq] + atomicAdd(&cursor[dq], 1);
        int2 val = make_int2(s << 6, __float_as_int(norm));  // pre-scaled src offset
        if (p < CAP) image[p] = val;
        else csr[gb + p] = val;  // statistical-tail fallback
    }
    __syncthreads();
    // zero-fill pads (cursor[tid] == real degree now)
    for (int p = lo + cursor[tid]; p < lo + degp; p++) {
        int2 z = make_int2(0, 0);
        if (p < CAP) image[p] = z;
        else csr[gb + p] = z;
    }
    __syncthreads();
    int lim = totalS < CAP ? totalS : CAP;
    int2* dstp = csr + gb;
    for (int i = tid; i < lim; i += 256) dstp[i] = image[i];
}

// ---- gather body: 8 subgroups x 8 lanes; lane = 8 channels (uint4 of bf16) ----
// rows are padded to x8 -> always full chunks. Result: 8 channel sums in r[0..7].
__device__ __forceinline__ void agg_body(int beg, int end, const int2* __restrict__ csr,
                                         const unsigned short* __restrict__ h,
                                         int sub, int qoff, float* r) {
    f32x2 a[4] = {{0, 0}, {0, 0}, {0, 0}, {0, 0}};
    f32x2 c[4] = {{0, 0}, {0, 0}, {0, 0}, {0, 0}};
    int j = beg;
    for (; j + 16 <= end; j += 16) {
        int2 e0 = csr[j + sub];
        int2 e1 = csr[j + 8 + sub];
        uint4 u0 = *(const uint4*)(h + e0.x + qoff);
        uint4 u1 = *(const uint4*)(h + e1.x + qoff);
        float n0 = __int_as_float(e0.y), n1 = __int_as_float(e1.y);
        f32x2 nn0 = {n0, n0}, nn1 = {n1, n1};
        a[0] += nn0 * (f32x2){bflo(u0.x), bfhi(u0.x)};
        a[1] += nn0 * (f32x2){bflo(u0.y), bfhi(u0.y)};
        a[2] += nn0 * (f32x2){bflo(u0.z), bfhi(u0.z)};
        a[3] += nn0 * (f32x2){bflo(u0.w), bfhi(u0.w)};
        c[0] += nn1 * (f32x2){bflo(u1.x), bfhi(u1.x)};
        c[1] += nn1 * (f32x2){bflo(u1.y), bfhi(u1.y)};
        c[2] += nn1 * (f32x2){bflo(u1.z), bfhi(u1.z)};
        c[3] += nn1 * (f32x2){bflo(u1.w), bfhi(u1.w)};
    }
    if (j < end) {  // exactly 8 padded edges remain
        int2 e0 = csr[j + sub];
        uint4 u0 = *(const uint4*)(h + e0.x + qoff);
        float n0 = __int_as_float(e0.y);
        f32x2 nn0 = {n0, n0};
        a[0] += nn0 * (f32x2){bflo(u0.x), bfhi(u0.x)};
        a[1] += nn0 * (f32x2){bflo(u0.y), bfhi(u0.y)};
        a[2] += nn0 * (f32x2){bflo(u0.z), bfhi(u0.z)};
        a[3] += nn0 * (f32x2){bflo(u0.w), bfhi(u0.w)};
    }
#pragma unroll
    for (int k = 0; k < 4; k++) {
        f32x2 s = a[k] + c[k];
        float v0 = s[0], v1 = s[1];
        v0 += __shfl_xor(v0, 8, 64);
        v0 += __shfl_xor(v0, 16, 64);
        v0 += __shfl_xor(v0, 32, 64);
        v1 += __shfl_xor(v1, 8, 64);
        v1 += __shfl_xor(v1, 16, 64);
        v1 += __shfl_xor(v1, 32, 64);
        r[2 * k] = v0;
        r[2 * k + 1] = v1;
    }
}

// ---- gather-aggregate + self loop + bias + relu -> bf16 out ----
__global__ void agg_relu_kernel(const int2* __restrict__ rowbounds, const int2* __restrict__ csr,
                                const float* __restrict__ dinv,
                                const unsigned short* __restrict__ h,
                                const float* __restrict__ b, unsigned short* __restrict__ out) {
    int tid = threadIdx.x;
    int wid = tid >> 6, lane = tid & 63;
    int sub = lane >> 3, q = lane & 7;
    int qoff = 8 * q;
    int node = blockIdx.x * 4 + wid;
    float dn = dinv[node];
    int2 rb = rowbounds[node];
    float r[8];
    agg_body(rb.x, rb.y, csr, h, sub, qoff, r);
    if (sub == 0) {
        uint4 su = *(const uint4*)(h + node * HID + qoff);
        float4 b0 = *(const float4*)&b[qoff];
        float4 b1 = *(const float4*)&b[qoff + 4];
        float dn2 = dn * dn;
        float v0 = fmaxf(r[0] + dn2 * bflo(su.x) + b0.x, 0.0f);
        float v1 = fmaxf(r[1] + dn2 * bfhi(su.x) + b0.y, 0.0f);
        float v2 = fmaxf(r[2] + dn2 * bflo(su.y) + b0.z, 0.0f);
        float v3 = fmaxf(r[3] + dn2 * bfhi(su.y) + b0.w, 0.0f);
        float v4 = fmaxf(r[4] + dn2 * bflo(su.z) + b1.x, 0.0f);
        float v5 = fmaxf(r[5] + dn2 * bfhi(su.z) + b1.y, 0.0f);
        float v6 = fmaxf(r[6] + dn2 * bflo(su.w) + b1.z, 0.0f);
        float v7 = fmaxf(r[7] + dn2 * bfhi(su.w) + b1.w, 0.0f);
        uint4 o;
        o.x = pack2bf(v0, v1); o.y = pack2bf(v2, v3);
        o.z = pack2bf(v4, v5); o.w = pack2bf(v6, v7);
        *(uint4*)(out + node * HID + qoff) = o;
    }
}

// ---- gather-aggregate + relu + fused mean-pool (pool fp32) ----
__global__ void agg_pool_kernel(const int2* __restrict__ rowbounds, const int2* __restrict__ csr,
                                const float* __restrict__ dinv,
                                const unsigned short* __restrict__ h,
                                const float* __restrict__ b, const int* __restrict__ batch,
                                float* __restrict__ pool, float* __restrict__ gcnt) {
    __shared__ float red[4][HID];
    __shared__ int gid[4];
    int tid = threadIdx.x;
    int wid = tid >> 6, lane = tid & 63;
    int sub = lane >> 3, q = lane & 7;
    int qoff = 8 * q;
    int node = blockIdx.x * 4 + wid;
    float dn = dinv[node];
    int2 rb = rowbounds[node];
    float r[8];
    agg_body(rb.x, rb.y, csr, h, sub, qoff, r);
    if (sub == 0) {
        uint4 su = *(const uint4*)(h + node * HID + qoff);
        float4 b0 = *(const float4*)&b[qoff];
        float4 b1 = *(const float4*)&b[qoff + 4];
        float dn2 = dn * dn;
        float4 v0, v1;
        v0.x = fmaxf(r[0] + dn2 * bflo(su.x) + b0.x, 0.0f);
        v0.y = fmaxf(r[1] + dn2 * bfhi(su.x) + b0.y, 0.0f);
        v0.z = fmaxf(r[2] + dn2 * bflo(su.y) + b0.z, 0.0f);
        v0.w = fmaxf(r[3] + dn2 * bfhi(su.y) + b0.w, 0.0f);
        v1.x = fmaxf(r[4] + dn2 * bflo(su.z) + b1.x, 0.0f);
        v1.y = fmaxf(r[5] + dn2 * bfhi(su.z) + b1.y, 0.0f);
        v1.z = fmaxf(r[6] + dn2 * bflo(su.w) + b1.z, 0.0f);
        v1.w = fmaxf(r[7] + dn2 * bfhi(su.w) + b1.w, 0.0f);
        *(float4*)&red[wid][qoff] = v0;
        *(float4*)&red[wid][qoff + 4] = v1;
    }
    if (lane == 0) gid[wid] = batch[node];
    __syncthreads();
    if (wid == 0) {
        int c = lane;
        float r0 = red[0][c], r1 = red[1][c], r2 = red[2][c], r3 = red[3][c];
        int g0 = gid[0], g1 = gid[1], g2 = gid[2], g3 = gid[3];
        if (g0 == g3) {
            atomicAdd(&pool[g0 * HID + c], r0 + r1 + r2 + r3);
            if (c == 0) atomicAdd(&gcnt[g0], 4.0f);
        } else {
            atomicAdd(&pool[g0 * HID + c], r0);
            atomicAdd(&pool[g1 * HID + c], r1);
            atomicAdd(&pool[g2 * HID + c], r2);
            atomicAdd(&pool[g3 * HID + c], r3);
            if (c == 0) {
                atomicAdd(&gcnt[g0], 1.0f);
                atomicAdd(&gcnt[g1], 1.0f);
                atomicAdd(&gcnt[g2], 1.0f);
                atomicAdd(&gcnt[g3], 1.0f);
            }
        }
    }
}

// ---- x @ W1 : [N,12] @ [12,64] -> bf16 ----
__global__ void xw1_kernel(const float* __restrict__ x, const float* __restrict__ W1,
                           unsigned short* __restrict__ h) {
    __shared__ float sW[IN_CH * HID];
    __shared__ float sx[16 * IN_CH];
    int tid = threadIdx.x;
    for (int i = tid; i < IN_CH * HID; i += 256) sW[i] = W1[i];
    int node0 = blockIdx.x * 16;
    if (tid < 16 * IN_CH) sx[tid] = x[node0 * IN_CH + tid];
    __syncthreads();
    int nl = tid >> 4, c4 = (tid & 15) * 4;
    float a0 = 0, a1 = 0, a2 = 0, a3 = 0;
#pragma unroll
    for (int k = 0; k < IN_CH; k++) {
        float xv = sx[nl * IN_CH + k];
        const float* w = &sW[k * HID + c4];
        a0 += xv * w[0]; a1 += xv * w[1]; a2 += xv * w[2]; a3 += xv * w[3];
    }
    ushort4 v = {f2bf(a0), f2bf(a1), f2bf(a2), f2bf(a3)};
    *(ushort4*)&h[(node0 + nl) * HID + c4] = v;
}

// ---- h @ W2 : [N,64] @ [64,64], bf16 in/out, fp32 compute ----
__global__ void hw2_kernel(const unsigned short* __restrict__ hin,
                           const float* __restrict__ W2, unsigned short* __restrict__ hout) {
    __shared__ float sW[HID * HID];
    __shared__ __align__(16) float sh[16 * HID];
    int tid = threadIdx.x;
    for (int i = tid; i < HID * HID; i += 256) sW[i] = W2[i];
    int node0 = blockIdx.x * 16;
    {
        uint2 u = *(const uint2*)&hin[node0 * HID + 4 * tid];
        sh[4 * tid + 0] = bflo(u.x); sh[4 * tid + 1] = bfhi(u.x);
        sh[4 * tid + 2] = bflo(u.y); sh[4 * tid + 3] = bfhi(u.y);
    }
    __syncthreads();
    int nl = tid >> 4, c4 = (tid & 15) * 4;
    float a0 = 0, a1 = 0, a2 = 0, a3 = 0;
#pragma unroll 8
    for (int k = 0; k < HID; k++) {
        float hv = sh[nl * HID + k];
        float4 w = *(const float4*)&sW[k * HID + c4];
        a0 += hv * w.x; a1 += hv * w.y; a2 += hv * w.z; a3 += hv * w.w;
    }
    ushort4 v = {f2bf(a0), f2bf(a1), f2bf(a2), f2bf(a3)};
    *(ushort4*)&hout[(node0 + nl) * HID + c4] = v;
}

// ---- final: out = sigmoid((pool/cnt) @ Wfc + bfc) ----
__global__ void final_kernel(const float* __restrict__ pool, const float* __restrict__ gcnt,
                             const float* __restrict__ Wfc, const float* __restrict__ bfc,
                             float* __restrict__ out) {
    int idx = blockIdx.x * 256 + threadIdx.x;
    if (idx >= N_GRAPHS * OUT_CH) return;
    int g = idx >> 2, o = idx & 3;
    float inv = 1.0f / fmaxf(gcnt[g], 1.0f);
    float acc = bfc[o];
#pragma unroll
    for (int k = 0; k < HID; k++) acc += pool[g * HID + k] * inv * Wfc[k * OUT_CH + o];
    out[idx] = 1.0f / (1.0f + expf(-acc));
}

extern "C" void kernel_launch(void* const* d_in, const int* in_sizes, int n_in,
                              void* d_out, int out_size, void* d_ws, size_t ws_size,
                              hipStream_t stream) {
    const float* x   = (const float*)d_in[0];
    const int* eidx  = (const int*)d_in[1];
    const int* batch = (const int*)d_in[2];
    const float* W1  = (const float*)d_in[3];
    const float* b1  = (const float*)d_in[4];
    const float* W2  = (const float*)d_in[5];
    const float* b2  = (const float*)d_in[6];
    const float* Wfc = (const float*)d_in[7];
    const float* bfc = (const float*)d_in[8];
    float* out = (float*)d_out;

    const int* src = eidx;
    const int* dst = eidx + N_EDGES;

    // workspace layout (~67 MB)
    unsigned short* hA = (unsigned short*)d_ws;              // 16 MB bf16
    unsigned short* hB = hA + (size_t)N_NODES * HID;         // 16 MB bf16
    int2*  csr    = (int2*)(hB + (size_t)N_NODES * HID);     // 23.1 MB {src<<6, norm}
    int*   staged = (int*)(csr + (size_t)NBUCK * CSR_STRIDE); // 9.4 MB bucket-strided
    float* dinv   = (float*)(staged + (size_t)NBUCK * STRIDE); // 512 KB
    int2*  rowbounds = (int2*)(dinv + N_NODES);              // 1 MB
    int*   bucket_count = (int*)(rowbounds + N_NODES);       // 2 KB
    float* pool   = (float*)(bucket_count + NBUCK);          // 512 KB
    float* gcnt   = pool + N_GRAPHS * HID;                   // 8 KB

    hipMemsetAsync(bucket_count, 0, (size_t)NBUCK * 4, stream);
    hipMemsetAsync(pool, 0, (size_t)(N_GRAPHS * HID + N_GRAPHS) * 4, stream);

    // CSR build: bucket sort -> padded rowbounds/dinv -> ordered fill (+pads)
    bucket_kernel<<<N_EDGES / CHUNK, 256, 0, stream>>>(src, dst, bucket_count, staged);
    count_kernel<<<NBUCK, 256, 0, stream>>>(bucket_count, staged, rowbounds, dinv);
    place_kernel<<<NBUCK, 256, 0, stream>>>(bucket_count, staged, rowbounds, dinv, csr);

    // layer 1
    xw1_kernel<<<N_NODES / 16, 256, 0, stream>>>(x, W1, hA);
    agg_relu_kernel<<<N_NODES / 4, 256, 0, stream>>>(rowbounds, csr, dinv, hA, b1, hB);

    // layer 2 (pool fused; h2 never materialized)
    hw2_kernel<<<N_NODES / 16, 256, 0, stream>>>(hB, W2, hA);
    agg_pool_kernel<<<N_NODES / 4, 256, 0, stream>>>(rowbounds, csr, dinv, hA, b2, batch,
                                                     pool, gcnt);

    // head
    final_kernel<<<(N_GRAPHS * OUT_CH + 255) / 256, 256, 0, stream>>>(pool, gcnt, Wfc, bfc, out);
}

// Round 9
// 279.618 us; speedup vs baseline: 1.8683x; 1.1563x over previous
//
#include <hip/hip_runtime.h>
#include <hip/hip_bf16.h>

// GCN. CSR via 2-pass LDS bucket sort (wave-contiguous global writes only;
// scattered 8B stores cost a full 64B line each on gfx950 TCC — measured R3-R5).
// Rows padded to x4. Agg: wave = 8 nodes (one per 8-lane subgroup), lane = 8
// channels, 4-deep edge unroll -> 32 gathers in flight, no shuffles, contiguous
// 1KB stores. Features bf16 (fp32 accumulate).

#define N_NODES 131072
#define N_EDGES 2097152
#define N_GRAPHS 2048
#define IN_CH 12
#define HID 64
#define OUT_CH 4
#define NBUCK 512          // buckets of 256 dst nodes
#define CHUNK 8192         // edges per bucket_kernel block
#define STRIDE 4608        // staging capacity per bucket (mean 4096, sd 64)
#define CSR_STRIDE 5120    // csr capacity per bucket (padded mean ~4500)
#define CAP 5120           // place_kernel LDS image capacity (40 KB)

typedef float f32x2 __attribute__((ext_vector_type(2)));

__device__ __forceinline__ unsigned short f2bf(float f) {
    unsigned u = __float_as_uint(f);
    return (unsigned short)((u + 0x7fffu + ((u >> 16) & 1u)) >> 16);  // RNE
}
__device__ __forceinline__ unsigned pack2bf(float lo, float hi) {
    return (unsigned)f2bf(lo) | ((unsigned)f2bf(hi) << 16);
}
__device__ __forceinline__ float bflo(unsigned v) { return __uint_as_float(v << 16); }
__device__ __forceinline__ float bfhi(unsigned v) { return __uint_as_float(v & 0xFFFF0000u); }

// ---- pass A: LDS bucket sort of edges by dst>>8 into strided staging ----
__global__ void bucket_kernel(const int* __restrict__ src, const int* __restrict__ dst,
                              int* __restrict__ bucket_count, int* __restrict__ staged) {
    __shared__ int hist[NBUCK];
    __shared__ int lscan[NBUCK];
    __shared__ int gbase[NBUCK];
    __shared__ int cursor[NBUCK];
    __shared__ int sorted[CHUNK];  // 32 KB
    int tid = threadIdx.x;
    int base = blockIdx.x * CHUNK;
    for (int b = tid; b < NBUCK; b += 256) { hist[b] = 0; cursor[b] = 0; }
    __syncthreads();
    for (int i = tid; i < CHUNK; i += 256) atomicAdd(&hist[dst[base + i] >> 8], 1);
    __syncthreads();
    for (int b = tid; b < NBUCK; b += 256) lscan[b] = hist[b];
    __syncthreads();
    for (int off = 1; off < NBUCK; off <<= 1) {
        int i0 = tid, i1 = tid + 256;
        int v0 = (i0 >= off) ? lscan[i0 - off] : 0;
        int v1 = (i1 >= off) ? lscan[i1 - off] : 0;
        __syncthreads();
        lscan[i0] += v0;
        lscan[i1] += v1;
        __syncthreads();
    }
    for (int b = tid; b < NBUCK; b += 256) gbase[b] = atomicAdd(&bucket_count[b], hist[b]);
    __syncthreads();
    // pack record = (d&255)<<17 | s   (s < 2^17)
    for (int i = tid; i < CHUNK; i += 256) {
        int d = dst[base + i];
        int s = src[base + i];
        int b = d >> 8;
        int start = lscan[b] - hist[b];
        int p = start + atomicAdd(&cursor[b], 1);
        sorted[p] = ((d & 255) << 17) | s;
    }
    __syncthreads();
    int wid = tid >> 6, lane = tid & 63;
    for (int b = wid; b < NBUCK; b += 4) {
        int cb = hist[b];
        int lbase = lscan[b] - cb;
        int gb = b * STRIDE + gbase[b];
        for (int k = lane; k < cb; k += 64) staged[gb + k] = sorted[lbase + k];
    }
}

// ---- per-bucket: fine degree count in LDS -> padded rowbounds, dinv ----
__global__ void count_kernel(const int* __restrict__ bucket_count, const int* __restrict__ staged,
                             int2* __restrict__ rowbounds, float* __restrict__ dinv) {
    __shared__ int cnt[256];
    __shared__ int scn[256];
    int b = blockIdx.x;
    int tid = threadIdx.x;
    int count = bucket_count[b];
    const int* st = staged + b * STRIDE;
    cnt[tid] = 0;
    __syncthreads();
    for (int i = tid; i < count; i += 256) atomicAdd(&cnt[(st[i] >> 17) & 255], 1);
    __syncthreads();
    int deg = cnt[tid];
    int degp = (deg + 3) & ~3;  // pad to x4
    scn[tid] = degp;
    __syncthreads();
    for (int off = 1; off < 256; off <<= 1) {
        int u = (tid >= off) ? scn[tid - off] : 0;
        __syncthreads();
        scn[tid] += u;
        __syncthreads();
    }
    int nbase = (b << 8) + tid;
    int gbeg = b * CSR_STRIDE + scn[tid] - degp;
    rowbounds[nbase] = make_int2(gbeg, gbeg + degp);
    dinv[nbase] = rsqrtf((float)deg + 1.0f);
}

// ---- per-bucket: place records (+zero pads) into CSR via LDS image ----
__global__ void place_kernel(const int* __restrict__ bucket_count, const int* __restrict__ staged,
                             const int2* __restrict__ rowbounds, const float* __restrict__ dinv,
                             int2* __restrict__ csr) {
    __shared__ int loff[256];
    __shared__ int cursor[256];
    __shared__ float ldinv[256];
    __shared__ int totalS;
    __shared__ int2 image[CAP];  // 40 KB
    int b = blockIdx.x;
    int tid = threadIdx.x;
    int nbase = (b << 8) + tid;
    int gb = b * CSR_STRIDE;
    int count = bucket_count[b];
    int2 rb = rowbounds[nbase];
    int lo = rb.x - gb;
    int degp = rb.y - rb.x;
    loff[tid] = lo;
    cursor[tid] = 0;
    ldinv[tid] = dinv[nbase];
    if (tid == 255) totalS = lo + degp;
    __syncthreads();
    const int* st = staged + b * STRIDE;
    for (int i = tid; i < count; i += 256) {
        int rec = st[i];
        int s = rec & 0x1FFFF;
        int dq = (rec >> 17) & 255;
        float norm = dinv[s] * ldinv[dq];  // dinv 512 KB -> L2-resident
        int p = loff[dq] + atomicAdd(&cursor[dq], 1);
        int2 val = make_int2(s << 6, __float_as_int(norm));  // pre-scaled src offset
        if (p < CAP) image[p] = val;
        else csr[gb + p] = val;  // statistical-tail fallback
    }
    __syncthreads();
    // zero-fill pads (cursor[tid] == real degree now)
    for (int p = lo + cursor[tid]; p < lo + degp; p++) {
        int2 z = make_int2(0, 0);
        if (p < CAP) image[p] = z;
        else csr[gb + p] = z;
    }
    __syncthreads();
    int lim = totalS < CAP ? totalS : CAP;
    int2* dstp = csr + gb;
    for (int i = tid; i < lim; i += 256) dstp[i] = image[i];
}

// ---- gather body: subgroup-private node; lane owns 8 channels; 4-deep unroll ----
__device__ __forceinline__ void agg_body(int beg, int end, const int2* __restrict__ csr,
                                         const unsigned short* __restrict__ h,
                                         int qoff, float* r) {
    f32x2 a0[4] = {{0, 0}, {0, 0}, {0, 0}, {0, 0}};
    f32x2 a1[4] = {{0, 0}, {0, 0}, {0, 0}, {0, 0}};
    f32x2 a2[4] = {{0, 0}, {0, 0}, {0, 0}, {0, 0}};
    f32x2 a3[4] = {{0, 0}, {0, 0}, {0, 0}, {0, 0}};
    for (int j = beg; j < end; j += 4) {  // rows padded to x4: no remainder
        int4 e01 = *(const int4*)(csr + j);
        int4 e23 = *(const int4*)(csr + j + 2);
        uint4 u0 = *(const uint4*)(h + e01.x + qoff);
        uint4 u1 = *(const uint4*)(h + e01.z + qoff);
        uint4 u2 = *(const uint4*)(h + e23.x + qoff);
        uint4 u3 = *(const uint4*)(h + e23.z + qoff);
        float n0 = __int_as_float(e01.y), n1 = __int_as_float(e01.w);
        float n2 = __int_as_float(e23.y), n3 = __int_as_float(e23.w);
        f32x2 nn0 = {n0, n0}, nn1 = {n1, n1}, nn2 = {n2, n2}, nn3 = {n3, n3};
        a0[0] += nn0 * (f32x2){bflo(u0.x), bfhi(u0.x)};
        a0[1] += nn0 * (f32x2){bflo(u0.y), bfhi(u0.y)};
        a0[2] += nn0 * (f32x2){bflo(u0.z), bfhi(u0.z)};
        a0[3] += nn0 * (f32x2){bflo(u0.w), bfhi(u0.w)};
        a1[0] += nn1 * (f32x2){bflo(u1.x), bfhi(u1.x)};
        a1[1] += nn1 * (f32x2){bflo(u1.y), bfhi(u1.y)};
        a1[2] += nn1 * (f32x2){bflo(u1.z), bfhi(u1.z)};
        a1[3] += nn1 * (f32x2){bflo(u1.w), bfhi(u1.w)};
        a2[0] += nn2 * (f32x2){bflo(u2.x), bfhi(u2.x)};
        a2[1] += nn2 * (f32x2){bflo(u2.y), bfhi(u2.y)};
        a2[2] += nn2 * (f32x2){bflo(u2.z), bfhi(u2.z)};
        a2[3] += nn2 * (f32x2){bflo(u2.w), bfhi(u2.w)};
        a3[0] += nn3 * (f32x2){bflo(u3.x), bfhi(u3.x)};
        a3[1] += nn3 * (f32x2){bflo(u3.y), bfhi(u3.y)};
        a3[2] += nn3 * (f32x2){bflo(u3.z), bfhi(u3.z)};
        a3[3] += nn3 * (f32x2){bflo(u3.w), bfhi(u3.w)};
    }
#pragma unroll
    for (int k = 0; k < 4; k++) {
        f32x2 s = (a0[k] + a1[k]) + (a2[k] + a3[k]);
        r[2 * k] = s[0];
        r[2 * k + 1] = s[1];
    }
}

// ---- gather-aggregate + self loop + bias + relu -> bf16 out (32 nodes/block) ----
__global__ void agg_relu_kernel(const int2* __restrict__ rowbounds, const int2* __restrict__ csr,
                                const float* __restrict__ dinv,
                                const unsigned short* __restrict__ h,
                                const float* __restrict__ b, unsigned short* __restrict__ out) {
    int tid = threadIdx.x;
    int w = tid >> 6, lane = tid & 63, sub = lane >> 3, q = lane & 7;
    int qoff = 8 * q;
    int node = (blockIdx.x * 4 + w) * 8 + sub;
    int2 rb = rowbounds[node];
    float dn = dinv[node];
    float r[8];
    agg_body(rb.x, rb.y, csr, h, qoff, r);
    uint4 su = *(const uint4*)(h + node * HID + qoff);
    float4 b0 = *(const float4*)&b[qoff];
    float4 b1 = *(const float4*)&b[qoff + 4];
    float dn2 = dn * dn;
    float v0 = fmaxf(r[0] + dn2 * bflo(su.x) + b0.x, 0.0f);
    float v1 = fmaxf(r[1] + dn2 * bfhi(su.x) + b0.y, 0.0f);
    float v2 = fmaxf(r[2] + dn2 * bflo(su.y) + b0.z, 0.0f);
    float v3 = fmaxf(r[3] + dn2 * bfhi(su.y) + b0.w, 0.0f);
    float v4 = fmaxf(r[4] + dn2 * bflo(su.z) + b1.x, 0.0f);
    float v5 = fmaxf(r[5] + dn2 * bfhi(su.z) + b1.y, 0.0f);
    float v6 = fmaxf(r[6] + dn2 * bflo(su.w) + b1.z, 0.0f);
    float v7 = fmaxf(r[7] + dn2 * bfhi(su.w) + b1.w, 0.0f);
    uint4 o;
    o.x = pack2bf(v0, v1); o.y = pack2bf(v2, v3);
    o.z = pack2bf(v4, v5); o.w = pack2bf(v6, v7);
    *(uint4*)(out + node * HID + qoff) = o;  // wave: 8 full rows = 1KB contiguous
}

// ---- gather-aggregate + relu + fused mean-pool (run-length flush) ----
__global__ void agg_pool_kernel(const int2* __restrict__ rowbounds, const int2* __restrict__ csr,
                                const float* __restrict__ dinv,
                                const unsigned short* __restrict__ h,
                                const float* __restrict__ b, const int* __restrict__ batch,
                                float* __restrict__ pool, float* __restrict__ gcnt) {
    __shared__ float red[32][HID];  // 8 KB
    __shared__ int gids[32];
    int tid = threadIdx.x;
    int w = tid >> 6, lane = tid & 63, sub = lane >> 3, q = lane & 7;
    int qoff = 8 * q;
    int node = (blockIdx.x * 4 + w) * 8 + sub;
    int2 rb = rowbounds[node];
    float dn = dinv[node];
    float r[8];
    agg_body(rb.x, rb.y, csr, h, qoff, r);
    uint4 su = *(const uint4*)(h + node * HID + qoff);
    float4 b0 = *(const float4*)&b[qoff];
    float4 b1 = *(const float4*)&b[qoff + 4];
    float dn2 = dn * dn;
    float4 v0, v1;
    v0.x = fmaxf(r[0] + dn2 * bflo(su.x) + b0.x, 0.0f);
    v0.y = fmaxf(r[1] + dn2 * bfhi(su.x) + b0.y, 0.0f);
    v0.z = fmaxf(r[2] + dn2 * bflo(su.y) + b0.z, 0.0f);
    v0.w = fmaxf(r[3] + dn2 * bfhi(su.y) + b0.w, 0.0f);
    v1.x = fmaxf(r[4] + dn2 * bflo(su.z) + b1.x, 0.0f);
    v1.y = fmaxf(r[5] + dn2 * bfhi(su.z) + b1.y, 0.0f);
    v1.z = fmaxf(r[6] + dn2 * bflo(su.w) + b1.z, 0.0f);
    v1.w = fmaxf(r[7] + dn2 * bfhi(su.w) + b1.w, 0.0f);
    int nl = w * 8 + sub;
    *(float4*)&red[nl][qoff] = v0;
    *(float4*)&red[nl][qoff + 4] = v1;
    if (q == 0) gids[nl] = batch[node];
    __syncthreads();
    if (tid < 64) {  // wave 0: run-length reduce 32 nodes (batch sorted)
        int c = tid;
        float acc = 0.0f;
        int cur = gids[0], cnt = 0;
        for (int n = 0; n < 32; n++) {
            int g = gids[n];
            if (g != cur) {
                atomicAdd(&pool[cur * HID + c], acc);
                if (c == 0) atomicAdd(&gcnt[cur], (float)cnt);
                acc = 0.0f; cnt = 0; cur = g;
            }
            acc += red[n][c];
            cnt++;
        }
        atomicAdd(&pool[cur * HID + c], acc);
        if (c == 0) atomicAdd(&gcnt[cur], (float)cnt);
    }
}

// ---- x @ W1 : [N,12] @ [12,64] -> bf16 ----
__global__ void xw1_kernel(const float* __restrict__ x, const float* __restrict__ W1,
                           unsigned short* __restrict__ h) {
    __shared__ float sW[IN_CH * HID];
    __shared__ float sx[16 * IN_CH];
    int tid = threadIdx.x;
    for (int i = tid; i < IN_CH * HID; i += 256) sW[i] = W1[i];
    int node0 = blockIdx.x * 16;
    if (tid < 16 * IN_CH) sx[tid] = x[node0 * IN_CH + tid];
    __syncthreads();
    int nl = tid >> 4, c4 = (tid & 15) * 4;
    float a0 = 0, a1 = 0, a2 = 0, a3 = 0;
#pragma unroll
    for (int k = 0; k < IN_CH; k++) {
        float xv = sx[nl * IN_CH + k];
        const float* w = &sW[k * HID + c4];
        a0 += xv * w[0]; a1 += xv * w[1]; a2 += xv * w[2]; a3 += xv * w[3];
    }
    ushort4 v = {f2bf(a0), f2bf(a1), f2bf(a2), f2bf(a3)};
    *(ushort4*)&h[(node0 + nl) * HID + c4] = v;
}

// ---- h @ W2 : [N,64] @ [64,64], bf16 in/out, fp32 compute ----
__global__ void hw2_kernel(const unsigned short* __restrict__ hin,
                           const float* __restrict__ W2, unsigned short* __restrict__ hout) {
    __shared__ float sW[HID * HID];
    __shared__ __align__(16) float sh[16 * HID];
    int tid = threadIdx.x;
    for (int i = tid; i < HID * HID; i += 256) sW[i] = W2[i];
    int node0 = blockIdx.x * 16;
    {
        uint2 u = *(const uint2*)&hin[node0 * HID + 4 * tid];
        sh[4 * tid + 0] = bflo(u.x); sh[4 * tid + 1] = bfhi(u.x);
        sh[4 * tid + 2] = bflo(u.y); sh[4 * tid + 3] = bfhi(u.y);
    }
    __syncthreads();
    int nl = tid >> 4, c4 = (tid & 15) * 4;
    float a0 = 0, a1 = 0, a2 = 0, a3 = 0;
#pragma unroll 8
    for (int k = 0; k < HID; k++) {
        float hv = sh[nl * HID + k];
        float4 w = *(const float4*)&sW[k * HID + c4];
        a0 += hv * w.x; a1 += hv * w.y; a2 += hv * w.z; a3 += hv * w.w;
    }
    ushort4 v = {f2bf(a0), f2bf(a1), f2bf(a2), f2bf(a3)};
    *(ushort4*)&hout[(node0 + nl) * HID + c4] = v;
}

// ---- final: out = sigmoid((pool/cnt) @ Wfc + bfc) ----
__global__ void final_kernel(const float* __restrict__ pool, const float* __restrict__ gcnt,
                             const float* __restrict__ Wfc, const float* __restrict__ bfc,
                             float* __restrict__ out) {
    int idx = blockIdx.x * 256 + threadIdx.x;
    if (idx >= N_GRAPHS * OUT_CH) return;
    int g = idx >> 2, o = idx & 3;
    float inv = 1.0f / fmaxf(gcnt[g], 1.0f);
    float acc = bfc[o];
#pragma unroll
    for (int k = 0; k < HID; k++) acc += pool[g * HID + k] * inv * Wfc[k * OUT_CH + o];
    out[idx] = 1.0f / (1.0f + expf(-acc));
}

extern "C" void kernel_launch(void* const* d_in, const int* in_sizes, int n_in,
                              void* d_out, int out_size, void* d_ws, size_t ws_size,
                              hipStream_t stream) {
    const float* x   = (const float*)d_in[0];
    const int* eidx  = (const int*)d_in[1];
    const int* batch = (const int*)d_in[2];
    const float* W1  = (const float*)d_in[3];
    const float* b1  = (const float*)d_in[4];
    const float* W2  = (const float*)d_in[5];
    const float* b2  = (const float*)d_in[6];
    const float* Wfc = (const float*)d_in[7];
    const float* bfc = (const float*)d_in[8];
    float* out = (float*)d_out;

    const int* src = eidx;
    const int* dst = eidx + N_EDGES;

    // workspace layout (~65 MB)
    unsigned short* hA = (unsigned short*)d_ws;              // 16 MB bf16
    unsigned short* hB = hA + (size_t)N_NODES * HID;         // 16 MB bf16
    int2*  csr    = (int2*)(hB + (size_t)N_NODES * HID);     // 21 MB {src<<6, norm}
    int*   staged = (int*)(csr + (size_t)NBUCK * CSR_STRIDE); // 9.4 MB bucket-strided
    float* dinv   = (float*)(staged + (size_t)NBUCK * STRIDE); // 512 KB
    int2*  rowbounds = (int2*)(dinv + N_NODES);              // 1 MB
    int*   bucket_count = (int*)(rowbounds + N_NODES);       // 2 KB
    float* pool   = (float*)(bucket_count + NBUCK);          // 512 KB
    float* gcnt   = pool + N_GRAPHS * HID;                   // 8 KB

    hipMemsetAsync(bucket_count, 0, (size_t)NBUCK * 4, stream);
    hipMemsetAsync(pool, 0, (size_t)(N_GRAPHS * HID + N_GRAPHS) * 4, stream);

    // CSR build: bucket sort -> padded rowbounds/dinv -> ordered fill (+pads)
    bucket_kernel<<<N_EDGES / CHUNK, 256, 0, stream>>>(src, dst, bucket_count, staged);
    count_kernel<<<NBUCK, 256, 0, stream>>>(bucket_count, staged, rowbounds, dinv);
    place_kernel<<<NBUCK, 256, 0, stream>>>(bucket_count, staged, rowbounds, dinv, csr);

    // layer 1
    xw1_kernel<<<N_NODES / 16, 256, 0, stream>>>(x, W1, hA);
    agg_relu_kernel<<<N_NODES / 32, 256, 0, stream>>>(rowbounds, csr, dinv, hA, b1, hB);

    // layer 2 (pool fused; h2 never materialized)
    hw2_kernel<<<N_NODES / 16, 256, 0, stream>>>(hB, W2, hA);
    agg_pool_kernel<<<N_NODES / 32, 256, 0, stream>>>(rowbounds, csr, dinv, hA, b2, batch,
                                                      pool, gcnt);

    // head
    final_kernel<<<(N_GRAPHS * OUT_CH + 255) / 256, 256, 0, stream>>>(pool, gcnt, Wfc, bfc, out);
}

// Round 10
// 250.242 us; speedup vs baseline: 2.0876x; 1.1174x over previous
//
#include <hip/hip_runtime.h>
#include <hip/hip_bf16.h>

// GCN. CSR via 2-pass LDS bucket sort (wave-contiguous global writes only;
// scattered 8B stores cost a full 64B line each on gfx950 TCC — measured R3-R5).
// bucket_kernel: 1024 threads (R9 showed 9.9% occupancy at 256 threads = 1
// block/CU; latency-serialized). Rows padded to x4. Agg: wave = 8 nodes (one
// per 8-lane subgroup), lane = 8 channels, 4-deep unroll -> 32 gathers in
// flight, no shuffles, contiguous 1KB stores. Features bf16 (fp32 accumulate).

#define N_NODES 131072
#define N_EDGES 2097152
#define N_GRAPHS 2048
#define IN_CH 12
#define HID 64
#define OUT_CH 4
#define NBUCK 512          // buckets of 256 dst nodes
#define CHUNK 8192         // edges per bucket_kernel block
#define STRIDE 4608        // staging capacity per bucket (mean 4096, sd 64)
#define CSR_STRIDE 5120    // csr capacity per bucket (padded mean ~4500)
#define CAP 5120           // place_kernel LDS image capacity (40 KB)

typedef float f32x2 __attribute__((ext_vector_type(2)));

__device__ __forceinline__ unsigned short f2bf(float f) {
    unsigned u = __float_as_uint(f);
    return (unsigned short)((u + 0x7fffu + ((u >> 16) & 1u)) >> 16);  // RNE
}
__device__ __forceinline__ unsigned pack2bf(float lo, float hi) {
    return (unsigned)f2bf(lo) | ((unsigned)f2bf(hi) << 16);
}
__device__ __forceinline__ float bflo(unsigned v) { return __uint_as_float(v << 16); }
__device__ __forceinline__ float bfhi(unsigned v) { return __uint_as_float(v & 0xFFFF0000u); }

// ---- pass A: LDS bucket sort of edges by dst>>8 into strided staging ----
__global__ __launch_bounds__(1024, 4)
void bucket_kernel(const int* __restrict__ src, const int* __restrict__ dst,
                   int* __restrict__ bucket_count, int* __restrict__ staged) {
    __shared__ int hist[NBUCK];
    __shared__ int lscan[NBUCK];
    __shared__ int gbase[NBUCK];
    __shared__ int cursor[NBUCK];
    __shared__ int sorted[CHUNK];  // 32 KB
    int tid = threadIdx.x;
    int base = blockIdx.x * CHUNK;
    if (tid < NBUCK) { hist[tid] = 0; cursor[tid] = 0; }
    __syncthreads();
    // load edges once into registers (coalesced), build histogram
    int d8[8], s8[8];
#pragma unroll
    for (int k = 0; k < 8; k++) {
        int i = base + k * 1024 + tid;
        d8[k] = dst[i];
        s8[k] = src[i];
        atomicAdd(&hist[d8[k] >> 8], 1);
    }
    __syncthreads();
    if (tid < NBUCK) lscan[tid] = hist[tid];
    __syncthreads();
    // Hillis-Steele inclusive scan over 512 (threads >= NBUCK just hit barriers)
    for (int off = 1; off < NBUCK; off <<= 1) {
        int u = (tid < NBUCK && tid >= off) ? lscan[tid - off] : 0;
        __syncthreads();
        if (tid < NBUCK) lscan[tid] += u;
        __syncthreads();
    }
    if (tid < NBUCK) gbase[tid] = atomicAdd(&bucket_count[tid], hist[tid]);
    __syncthreads();
    // place: pack record = (d&255)<<17 | s   (s < 2^17)
#pragma unroll
    for (int k = 0; k < 8; k++) {
        int b = d8[k] >> 8;
        int start = lscan[b] - hist[b];
        int p = start + atomicAdd(&cursor[b], 1);
        sorted[p] = ((d8[k] & 255) << 17) | s8[k];
    }
    __syncthreads();
    // flush: each wave drains 4 buckets at once (16 lanes per bucket)
    int wid = tid >> 6, lane = tid & 63;
    int g16 = lane >> 4, k16 = lane & 15;
    for (int b0 = wid * 4; b0 < NBUCK; b0 += 64) {  // 16 waves x 4 buckets
        int b = b0 + g16;
        int cb = hist[b];
        int lbase = lscan[b] - cb;
        int gb = b * STRIDE + gbase[b];
        for (int k = k16; k < cb; k += 16) staged[gb + k] = sorted[lbase + k];
    }
}

// ---- per-bucket: fine degree count in LDS -> padded rowbounds, dinv ----
__global__ void count_kernel(const int* __restrict__ bucket_count, const int* __restrict__ staged,
                             int2* __restrict__ rowbounds, float* __restrict__ dinv) {
    __shared__ int cnt[256];
    __shared__ int scn[256];
    int b = blockIdx.x;
    int tid = threadIdx.x;
    int count = bucket_count[b];
    const int* st = staged + b * STRIDE;
    cnt[tid] = 0;
    __syncthreads();
    for (int i = tid; i < count; i += 256) atomicAdd(&cnt[(st[i] >> 17) & 255], 1);
    __syncthreads();
    int deg = cnt[tid];
    int degp = (deg + 3) & ~3;  // pad to x4
    scn[tid] = degp;
    __syncthreads();
    for (int off = 1; off < 256; off <<= 1) {
        int u = (tid >= off) ? scn[tid - off] : 0;
        __syncthreads();
        scn[tid] += u;
        __syncthreads();
    }
    int nbase = (b << 8) + tid;
    int gbeg = b * CSR_STRIDE + scn[tid] - degp;
    rowbounds[nbase] = make_int2(gbeg, gbeg + degp);
    dinv[nbase] = rsqrtf((float)deg + 1.0f);
}

// ---- per-bucket: place records (+zero pads) into CSR via LDS image ----
__global__ void place_kernel(const int* __restrict__ bucket_count, const int* __restrict__ staged,
                             const int2* __restrict__ rowbounds, const float* __restrict__ dinv,
                             int2* __restrict__ csr) {
    __shared__ int loff[256];
    __shared__ int cursor[256];
    __shared__ float ldinv[256];
    __shared__ int totalS;
    __shared__ int2 image[CAP];  // 40 KB
    int b = blockIdx.x;
    int tid = threadIdx.x;
    int nbase = (b << 8) + tid;
    int gb = b * CSR_STRIDE;
    int count = bucket_count[b];
    int2 rb = rowbounds[nbase];
    int lo = rb.x - gb;
    int degp = rb.y - rb.x;
    loff[tid] = lo;
    cursor[tid] = 0;
    ldinv[tid] = dinv[nbase];
    if (tid == 255) totalS = lo + degp;
    __syncthreads();
    const int* st = staged + b * STRIDE;
    for (int i = tid; i < count; i += 256) {
        int rec = st[i];
        int s = rec & 0x1FFFF;
        int dq = (rec >> 17) & 255;
        float norm = dinv[s] * ldinv[dq];  // dinv 512 KB -> L2-resident
        int p = loff[dq] + atomicAdd(&cursor[dq], 1);
        int2 val = make_int2(s << 6, __float_as_int(norm));  // pre-scaled src offset
        if (p < CAP) image[p] = val;
        else csr[gb + p] = val;  // statistical-tail fallback
    }
    __syncthreads();
    // zero-fill pads (cursor[tid] == real degree now)
    for (int p = lo + cursor[tid]; p < lo + degp; p++) {
        int2 z = make_int2(0, 0);
        if (p < CAP) image[p] = z;
        else csr[gb + p] = z;
    }
    __syncthreads();
    int lim = totalS < CAP ? totalS : CAP;
    int2* dstp = csr + gb;
    for (int i = tid; i < lim; i += 256) dstp[i] = image[i];
}

// ---- gather body: subgroup-private node; lane owns 8 channels; 4-deep unroll ----
__device__ __forceinline__ void agg_body(int beg, int end, const int2* __restrict__ csr,
                                         const unsigned short* __restrict__ h,
                                         int qoff, float* r) {
    f32x2 a0[4] = {{0, 0}, {0, 0}, {0, 0}, {0, 0}};
    f32x2 a1[4] = {{0, 0}, {0, 0}, {0, 0}, {0, 0}};
    f32x2 a2[4] = {{0, 0}, {0, 0}, {0, 0}, {0, 0}};
    f32x2 a3[4] = {{0, 0}, {0, 0}, {0, 0}, {0, 0}};
    for (int j = beg; j < end; j += 4) {  // rows padded to x4: no remainder
        int4 e01 = *(const int4*)(csr + j);
        int4 e23 = *(const int4*)(csr + j + 2);
        uint4 u0 = *(const uint4*)(h + e01.x + qoff);
        uint4 u1 = *(const uint4*)(h + e01.z + qoff);
        uint4 u2 = *(const uint4*)(h + e23.x + qoff);
        uint4 u3 = *(const uint4*)(h + e23.z + qoff);
        float n0 = __int_as_float(e01.y), n1 = __int_as_float(e01.w);
        float n2 = __int_as_float(e23.y), n3 = __int_as_float(e23.w);
        f32x2 nn0 = {n0, n0}, nn1 = {n1, n1}, nn2 = {n2, n2}, nn3 = {n3, n3};
        a0[0] += nn0 * (f32x2){bflo(u0.x), bfhi(u0.x)};
        a0[1] += nn0 * (f32x2){bflo(u0.y), bfhi(u0.y)};
        a0[2] += nn0 * (f32x2){bflo(u0.z), bfhi(u0.z)};
        a0[3] += nn0 * (f32x2){bflo(u0.w), bfhi(u0.w)};
        a1[0] += nn1 * (f32x2){bflo(u1.x), bfhi(u1.x)};
        a1[1] += nn1 * (f32x2){bflo(u1.y), bfhi(u1.y)};
        a1[2] += nn1 * (f32x2){bflo(u1.z), bfhi(u1.z)};
        a1[3] += nn1 * (f32x2){bflo(u1.w), bfhi(u1.w)};
        a2[0] += nn2 * (f32x2){bflo(u2.x), bfhi(u2.x)};
        a2[1] += nn2 * (f32x2){bflo(u2.y), bfhi(u2.y)};
        a2[2] += nn2 * (f32x2){bflo(u2.z), bfhi(u2.z)};
        a2[3] += nn2 * (f32x2){bflo(u2.w), bfhi(u2.w)};
        a3[0] += nn3 * (f32x2){bflo(u3.x), bfhi(u3.x)};
        a3[1] += nn3 * (f32x2){bflo(u3.y), bfhi(u3.y)};
        a3[2] += nn3 * (f32x2){bflo(u3.z), bfhi(u3.z)};
        a3[3] += nn3 * (f32x2){bflo(u3.w), bfhi(u3.w)};
    }
#pragma unroll
    for (int k = 0; k < 4; k++) {
        f32x2 s = (a0[k] + a1[k]) + (a2[k] + a3[k]);
        r[2 * k] = s[0];
        r[2 * k + 1] = s[1];
    }
}

// ---- gather-aggregate + self loop + bias + relu -> bf16 out (32 nodes/block) ----
__global__ void agg_relu_kernel(const int2* __restrict__ rowbounds, const int2* __restrict__ csr,
                                const float* __restrict__ dinv,
                                const unsigned short* __restrict__ h,
                                const float* __restrict__ b, unsigned short* __restrict__ out) {
    int tid = threadIdx.x;
    int w = tid >> 6, lane = tid & 63, sub = lane >> 3, q = lane & 7;
    int qoff = 8 * q;
    int node = (blockIdx.x * 4 + w) * 8 + sub;
    int2 rb = rowbounds[node];
    float dn = dinv[node];
    float r[8];
    agg_body(rb.x, rb.y, csr, h, qoff, r);
    uint4 su = *(const uint4*)(h + node * HID + qoff);
    float4 b0 = *(const float4*)&b[qoff];
    float4 b1 = *(const float4*)&b[qoff + 4];
    float dn2 = dn * dn;
    float v0 = fmaxf(r[0] + dn2 * bflo(su.x) + b0.x, 0.0f);
    float v1 = fmaxf(r[1] + dn2 * bfhi(su.x) + b0.y, 0.0f);
    float v2 = fmaxf(r[2] + dn2 * bflo(su.y) + b0.z, 0.0f);
    float v3 = fmaxf(r[3] + dn2 * bfhi(su.y) + b0.w, 0.0f);
    float v4 = fmaxf(r[4] + dn2 * bflo(su.z) + b1.x, 0.0f);
    float v5 = fmaxf(r[5] + dn2 * bfhi(su.z) + b1.y, 0.0f);
    float v6 = fmaxf(r[6] + dn2 * bflo(su.w) + b1.z, 0.0f);
    float v7 = fmaxf(r[7] + dn2 * bfhi(su.w) + b1.w, 0.0f);
    uint4 o;
    o.x = pack2bf(v0, v1); o.y = pack2bf(v2, v3);
    o.z = pack2bf(v4, v5); o.w = pack2bf(v6, v7);
    *(uint4*)(out + node * HID + qoff) = o;  // wave: 8 full rows = 1KB contiguous
}

// ---- gather-aggregate + relu + fused mean-pool (run-length flush) ----
__global__ void agg_pool_kernel(const int2* __restrict__ rowbounds, const int2* __restrict__ csr,
                                const float* __restrict__ dinv,
                                const unsigned short* __restrict__ h,
                                const float* __restrict__ b, const int* __restrict__ batch,
                                float* __restrict__ pool, float* __restrict__ gcnt) {
    __shared__ float red[32][HID];  // 8 KB
    __shared__ int gids[32];
    int tid = threadIdx.x;
    int w = tid >> 6, lane = tid & 63, sub = lane >> 3, q = lane & 7;
    int qoff = 8 * q;
    int node = (blockIdx.x * 4 + w) * 8 + sub;
    int2 rb = rowbounds[node];
    float dn = dinv[node];
    float r[8];
    agg_body(rb.x, rb.y, csr, h, qoff, r);
    uint4 su = *(const uint4*)(h + node * HID + qoff);
    float4 b0 = *(const float4*)&b[qoff];
    float4 b1 = *(const float4*)&b[qoff + 4];
    float dn2 = dn * dn;
    float4 v0, v1;
    v0.x = fmaxf(r[0] + dn2 * bflo(su.x) + b0.x, 0.0f);
    v0.y = fmaxf(r[1] + dn2 * bfhi(su.x) + b0.y, 0.0f);
    v0.z = fmaxf(r[2] + dn2 * bflo(su.y) + b0.z, 0.0f);
    v0.w = fmaxf(r[3] + dn2 * bfhi(su.y) + b0.w, 0.0f);
    v1.x = fmaxf(r[4] + dn2 * bflo(su.z) + b1.x, 0.0f);
    v1.y = fmaxf(r[5] + dn2 * bfhi(su.z) + b1.y, 0.0f);
    v1.z = fmaxf(r[6] + dn2 * bflo(su.w) + b1.z, 0.0f);
    v1.w = fmaxf(r[7] + dn2 * bfhi(su.w) + b1.w, 0.0f);
    int nl = w * 8 + sub;
    *(float4*)&red[nl][qoff] = v0;
    *(float4*)&red[nl][qoff + 4] = v1;
    if (q == 0) gids[nl] = batch[node];
    __syncthreads();
    if (tid < 64) {  // wave 0: run-length reduce 32 nodes (batch sorted)
        int c = tid;
        float acc = 0.0f;
        int cur = gids[0], cnt = 0;
        for (int n = 0; n < 32; n++) {
            int g = gids[n];
            if (g != cur) {
                atomicAdd(&pool[cur * HID + c], acc);
                if (c == 0) atomicAdd(&gcnt[cur], (float)cnt);
                acc = 0.0f; cnt = 0; cur = g;
            }
            acc += red[n][c];
            cnt++;
        }
        atomicAdd(&pool[cur * HID + c], acc);
        if (c == 0) atomicAdd(&gcnt[cur], (float)cnt);
    }
}

// ---- x @ W1 : [N,12] @ [12,64] -> bf16 ----
__global__ void xw1_kernel(const float* __restrict__ x, const float* __restrict__ W1,
                           unsigned short* __restrict__ h) {
    __shared__ float sW[IN_CH * HID];
    __shared__ float sx[16 * IN_CH];
    int tid = threadIdx.x;
    for (int i = tid; i < IN_CH * HID; i += 256) sW[i] = W1[i];
    int node0 = blockIdx.x * 16;
    if (tid < 16 * IN_CH) sx[tid] = x[node0 * IN_CH + tid];
    __syncthreads();
    int nl = tid >> 4, c4 = (tid & 15) * 4;
    float a0 = 0, a1 = 0, a2 = 0, a3 = 0;
#pragma unroll
    for (int k = 0; k < IN_CH; k++) {
        float xv = sx[nl * IN_CH + k];
        const float* w = &sW[k * HID + c4];
        a0 += xv * w[0]; a1 += xv * w[1]; a2 += xv * w[2]; a3 += xv * w[3];
    }
    ushort4 v = {f2bf(a0), f2bf(a1), f2bf(a2), f2bf(a3)};
    *(ushort4*)&h[(node0 + nl) * HID + c4] = v;
}

// ---- h @ W2 : [N,64] @ [64,64], bf16 in/out, fp32 compute ----
__global__ void hw2_kernel(const unsigned short* __restrict__ hin,
                           const float* __restrict__ W2, unsigned short* __restrict__ hout) {
    __shared__ float sW[HID * HID];
    __shared__ __align__(16) float sh[16 * HID];
    int tid = threadIdx.x;
    for (int i = tid; i < HID * HID; i += 256) sW[i] = W2[i];
    int node0 = blockIdx.x * 16;
    {
        uint2 u = *(const uint2*)&hin[node0 * HID + 4 * tid];
        sh[4 * tid + 0] = bflo(u.x); sh[4 * tid + 1] = bfhi(u.x);
        sh[4 * tid + 2] = bflo(u.y); sh[4 * tid + 3] = bfhi(u.y);
    }
    __syncthreads();
    int nl = tid >> 4, c4 = (tid & 15) * 4;
    float a0 = 0, a1 = 0, a2 = 0, a3 = 0;
#pragma unroll 8
    for (int k = 0; k < HID; k++) {
        float hv = sh[nl * HID + k];
        float4 w = *(const float4*)&sW[k * HID + c4];
        a0 += hv * w.x; a1 += hv * w.y; a2 += hv * w.z; a3 += hv * w.w;
    }
    ushort4 v = {f2bf(a0), f2bf(a1), f2bf(a2), f2bf(a3)};
    *(ushort4*)&hout[(node0 + nl) * HID + c4] = v;
}

// ---- final: out = sigmoid((pool/cnt) @ Wfc + bfc) ----
__global__ void final_kernel(const float* __restrict__ pool, const float* __restrict__ gcnt,
                             const float* __restrict__ Wfc, const float* __restrict__ bfc,
                             float* __restrict__ out) {
    int idx = blockIdx.x * 256 + threadIdx.x;
    if (idx >= N_GRAPHS * OUT_CH) return;
    int g = idx >> 2, o = idx & 3;
    float inv = 1.0f / fmaxf(gcnt[g], 1.0f);
    float acc = bfc[o];
#pragma unroll
    for (int k = 0; k < HID; k++) acc += pool[g * HID + k] * inv * Wfc[k * OUT_CH + o];
    out[idx] = 1.0f / (1.0f + expf(-acc));
}

extern "C" void kernel_launch(void* const* d_in, const int* in_sizes, int n_in,
                              void* d_out, int out_size, void* d_ws, size_t ws_size,
                              hipStream_t stream) {
    const float* x   = (const float*)d_in[0];
    const int* eidx  = (const int*)d_in[1];
    const int* batch = (const int*)d_in[2];
    const float* W1  = (const float*)d_in[3];
    const float* b1  = (const float*)d_in[4];
    const float* W2  = (const float*)d_in[5];
    const float* b2  = (const float*)d_in[6];
    const float* Wfc = (const float*)d_in[7];
    const float* bfc = (const float*)d_in[8];
    float* out = (float*)d_out;

    const int* src = eidx;
    const int* dst = eidx + N_EDGES;

    // workspace layout (~65 MB)
    unsigned short* hA = (unsigned short*)d_ws;              // 16 MB bf16
    unsigned short* hB = hA + (size_t)N_NODES * HID;         // 16 MB bf16
    int2*  csr    = (int2*)(hB + (size_t)N_NODES * HID);     // 21 MB {src<<6, norm}
    int*   staged = (int*)(csr + (size_t)NBUCK * CSR_STRIDE); // 9.4 MB bucket-strided
    float* dinv   = (float*)(staged + (size_t)NBUCK * STRIDE); // 512 KB
    int2*  rowbounds = (int2*)(dinv + N_NODES);              // 1 MB
    int*   bucket_count = (int*)(rowbounds + N_NODES);       // 2 KB
    float* pool   = (float*)(bucket_count + NBUCK);          // 512 KB
    float* gcnt   = pool + N_GRAPHS * HID;                   // 8 KB

    hipMemsetAsync(bucket_count, 0, (size_t)NBUCK * 4, stream);
    hipMemsetAsync(pool, 0, (size_t)(N_GRAPHS * HID + N_GRAPHS) * 4, stream);

    // CSR build: bucket sort -> padded rowbounds/dinv -> ordered fill (+pads)
    bucket_kernel<<<N_EDGES / CHUNK, 1024, 0, stream>>>(src, dst, bucket_count, staged);
    count_kernel<<<NBUCK, 256, 0, stream>>>(bucket_count, staged, rowbounds, dinv);
    place_kernel<<<NBUCK, 256, 0, stream>>>(bucket_count, staged, rowbounds, dinv, csr);

    // layer 1
    xw1_kernel<<<N_NODES / 16, 256, 0, stream>>>(x, W1, hA);
    agg_relu_kernel<<<N_NODES / 32, 256, 0, stream>>>(rowbounds, csr, dinv, hA, b1, hB);

    // layer 2 (pool fused; h2 never materialized)
    hw2_kernel<<<N_NODES / 16, 256, 0, stream>>>(hB, W2, hA);
    agg_pool_kernel<<<N_NODES / 32, 256, 0, stream>>>(rowbounds, csr, dinv, hA, b2, batch,
                                                      pool, gcnt);

    // head
    final_kernel<<<(N_GRAPHS * OUT_CH + 255) / 256, 256, 0, stream>>>(pool, gcnt, Wfc, bfc, out);
}

// Round 11
// 233.272 us; speedup vs baseline: 2.2395x; 1.0727x over previous
//
#include <hip/hip_runtime.h>
#include <hip/hip_bf16.h>

// GCN. CSR via 2-pass LDS bucket sort (wave-contiguous global writes only).
// Layer 1 exploits agg(xW) = agg(x)W: gather the 16-ch-padded bf16 x table
// (4 MB, ~L2-resident/XCD) instead of the 64-ch h table (16 MB) — the agg
// fetch floor is 8 XCDs x table size (measured R7-R10). Rows padded to x4.
// Layer-2 agg: wave = 8 nodes, lane = 8 ch, 4-deep unroll. bf16 feats, fp32 acc.

#define N_NODES 131072
#define N_EDGES 2097152
#define N_GRAPHS 2048
#define IN_CH 12
#define HID 64
#define OUT_CH 4
#define NBUCK 512          // buckets of 256 dst nodes
#define CHUNK 8192         // edges per bucket_kernel block
#define STRIDE 4608        // staging capacity per bucket (mean 4096, sd 64)
#define CSR_STRIDE 5120    // csr capacity per bucket (padded mean ~4500)
#define CAP 5120           // place_kernel LDS image capacity (40 KB)

typedef float f32x2 __attribute__((ext_vector_type(2)));

__device__ __forceinline__ unsigned short f2bf(float f) {
    unsigned u = __float_as_uint(f);
    return (unsigned short)((u + 0x7fffu + ((u >> 16) & 1u)) >> 16);  // RNE
}
__device__ __forceinline__ unsigned pack2bf(float lo, float hi) {
    return (unsigned)f2bf(lo) | ((unsigned)f2bf(hi) << 16);
}
__device__ __forceinline__ float bflo(unsigned v) { return __uint_as_float(v << 16); }
__device__ __forceinline__ float bfhi(unsigned v) { return __uint_as_float(v & 0xFFFF0000u); }

// ---- pass A: LDS bucket sort of edges by dst>>8 into strided staging ----
__global__ __launch_bounds__(1024, 4)
void bucket_kernel(const int* __restrict__ src, const int* __restrict__ dst,
                   int* __restrict__ bucket_count, int* __restrict__ staged) {
    __shared__ int hist[NBUCK];
    __shared__ int lscan[NBUCK];
    __shared__ int gbase[NBUCK];
    __shared__ int cursor[NBUCK];
    __shared__ int sorted[CHUNK];  // 32 KB
    int tid = threadIdx.x;
    int base = blockIdx.x * CHUNK;
    if (tid < NBUCK) { hist[tid] = 0; cursor[tid] = 0; }
    __syncthreads();
    int d8[8], s8[8];
#pragma unroll
    for (int k = 0; k < 8; k++) {
        int i = base + k * 1024 + tid;
        d8[k] = dst[i];
        s8[k] = src[i];
        atomicAdd(&hist[d8[k] >> 8], 1);
    }
    __syncthreads();
    if (tid < NBUCK) lscan[tid] = hist[tid];
    __syncthreads();
    for (int off = 1; off < NBUCK; off <<= 1) {
        int u = (tid < NBUCK && tid >= off) ? lscan[tid - off] : 0;
        __syncthreads();
        if (tid < NBUCK) lscan[tid] += u;
        __syncthreads();
    }
    if (tid < NBUCK) gbase[tid] = atomicAdd(&bucket_count[tid], hist[tid]);
    __syncthreads();
#pragma unroll
    for (int k = 0; k < 8; k++) {
        int b = d8[k] >> 8;
        int start = lscan[b] - hist[b];
        int p = start + atomicAdd(&cursor[b], 1);
        sorted[p] = ((d8[k] & 255) << 17) | s8[k];
    }
    __syncthreads();
    int wid = tid >> 6, lane = tid & 63;
    int g16 = lane >> 4, k16 = lane & 15;
    for (int b0 = wid * 4; b0 < NBUCK; b0 += 64) {
        int b = b0 + g16;
        int cb = hist[b];
        int lbase = lscan[b] - cb;
        int gb = b * STRIDE + gbase[b];
        for (int k = k16; k < cb; k += 16) staged[gb + k] = sorted[lbase + k];
    }
}

// ---- per-bucket: fine degree count in LDS -> padded rowbounds, dinv ----
__global__ void count_kernel(const int* __restrict__ bucket_count, const int* __restrict__ staged,
                             int2* __restrict__ rowbounds, float* __restrict__ dinv) {
    __shared__ int cnt[256];
    __shared__ int scn[256];
    int b = blockIdx.x;
    int tid = threadIdx.x;
    int count = bucket_count[b];
    const int* st = staged + b * STRIDE;
    cnt[tid] = 0;
    __syncthreads();
    for (int i = tid; i < count; i += 256) atomicAdd(&cnt[(st[i] >> 17) & 255], 1);
    __syncthreads();
    int deg = cnt[tid];
    int degp = (deg + 3) & ~3;  // pad to x4
    scn[tid] = degp;
    __syncthreads();
    for (int off = 1; off < 256; off <<= 1) {
        int u = (tid >= off) ? scn[tid - off] : 0;
        __syncthreads();
        scn[tid] += u;
        __syncthreads();
    }
    int nbase = (b << 8) + tid;
    int gbeg = b * CSR_STRIDE + scn[tid] - degp;
    rowbounds[nbase] = make_int2(gbeg, gbeg + degp);
    dinv[nbase] = rsqrtf((float)deg + 1.0f);
}

// ---- per-bucket: place records (+zero pads) into CSR via LDS image ----
__global__ void place_kernel(const int* __restrict__ bucket_count, const int* __restrict__ staged,
                             const int2* __restrict__ rowbounds, const float* __restrict__ dinv,
                             int2* __restrict__ csr) {
    __shared__ int loff[256];
    __shared__ int cursor[256];
    __shared__ float ldinv[256];
    __shared__ int totalS;
    __shared__ int2 image[CAP];  // 40 KB
    int b = blockIdx.x;
    int tid = threadIdx.x;
    int nbase = (b << 8) + tid;
    int gb = b * CSR_STRIDE;
    int count = bucket_count[b];
    int2 rb = rowbounds[nbase];
    int lo = rb.x - gb;
    int degp = rb.y - rb.x;
    loff[tid] = lo;
    cursor[tid] = 0;
    ldinv[tid] = dinv[nbase];
    if (tid == 255) totalS = lo + degp;
    __syncthreads();
    const int* st = staged + b * STRIDE;
    for (int i = tid; i < count; i += 256) {
        int rec = st[i];
        int s = rec & 0x1FFFF;
        int dq = (rec >> 17) & 255;
        float norm = dinv[s] * ldinv[dq];  // dinv 512 KB -> L2-resident
        int p = loff[dq] + atomicAdd(&cursor[dq], 1);
        int2 val = make_int2(s << 6, __float_as_int(norm));  // pre-scaled src offset (x64)
        if (p < CAP) image[p] = val;
        else csr[gb + p] = val;  // statistical-tail fallback
    }
    __syncthreads();
    for (int p = lo + cursor[tid]; p < lo + degp; p++) {
        int2 z = make_int2(0, 0);
        if (p < CAP) image[p] = z;
        else csr[gb + p] = z;
    }
    __syncthreads();
    int lim = totalS < CAP ? totalS : CAP;
    int2* dstp = csr + gb;
    for (int i = tid; i < lim; i += 256) dstp[i] = image[i];
}

// ---- x fp32[N,12] -> bf16[N,16] zero-padded ----
__global__ void xcast_kernel(const float* __restrict__ x, unsigned short* __restrict__ xb) {
    int n = blockIdx.x * 256 + threadIdx.x;
    const float* xp = x + n * IN_CH;
    unsigned o[8];
#pragma unroll
    for (int k = 0; k < 6; k++) o[k] = pack2bf(xp[2 * k], xp[2 * k + 1]);
    o[6] = 0; o[7] = 0;
    uint4* dst = (uint4*)(xb + n * 16);
    dst[0] = make_uint4(o[0], o[1], o[2], o[3]);
    dst[1] = make_uint4(o[4], o[5], o[6], o[7]);
}

// ---- layer-1 aggregation over the small x table: wave = 32 nodes,
//      2-lane subgroups, lane = 8 of 16 channels; self-loop fused ----
__global__ void agg_x_kernel(const int2* __restrict__ rowbounds, const int2* __restrict__ csr,
                             const float* __restrict__ dinv,
                             const unsigned short* __restrict__ xb, float* __restrict__ aggx) {
    int tid = threadIdx.x;
    int w = tid >> 6, lane = tid & 63, sub = lane >> 1, p = lane & 1;
    int qoff = 8 * p;
    int node = (blockIdx.x * 4 + w) * 32 + sub;
    int2 rb = rowbounds[node];
    float dn = dinv[node];
    f32x2 a0[4] = {{0, 0}, {0, 0}, {0, 0}, {0, 0}};
    f32x2 a1[4] = {{0, 0}, {0, 0}, {0, 0}, {0, 0}};
    f32x2 a2[4] = {{0, 0}, {0, 0}, {0, 0}, {0, 0}};
    f32x2 a3[4] = {{0, 0}, {0, 0}, {0, 0}, {0, 0}};
    for (int j = rb.x; j < rb.y; j += 4) {  // padded x4: no remainder
        int4 e01 = *(const int4*)(csr + j);
        int4 e23 = *(const int4*)(csr + j + 2);
        uint4 u0 = *(const uint4*)(xb + (e01.x >> 2) + qoff);  // src<<6 -> x16 row
        uint4 u1 = *(const uint4*)(xb + (e01.z >> 2) + qoff);
        uint4 u2 = *(const uint4*)(xb + (e23.x >> 2) + qoff);
        uint4 u3 = *(const uint4*)(xb + (e23.z >> 2) + qoff);
        float n0 = __int_as_float(e01.y), n1 = __int_as_float(e01.w);
        float n2 = __int_as_float(e23.y), n3 = __int_as_float(e23.w);
        f32x2 nn0 = {n0, n0}, nn1 = {n1, n1}, nn2 = {n2, n2}, nn3 = {n3, n3};
        a0[0] += nn0 * (f32x2){bflo(u0.x), bfhi(u0.x)};
        a0[1] += nn0 * (f32x2){bflo(u0.y), bfhi(u0.y)};
        a0[2] += nn0 * (f32x2){bflo(u0.z), bfhi(u0.z)};
        a0[3] += nn0 * (f32x2){bflo(u0.w), bfhi(u0.w)};
        a1[0] += nn1 * (f32x2){bflo(u1.x), bfhi(u1.x)};
        a1[1] += nn1 * (f32x2){bflo(u1.y), bfhi(u1.y)};
        a1[2] += nn1 * (f32x2){bflo(u1.z), bfhi(u1.z)};
        a1[3] += nn1 * (f32x2){bflo(u1.w), bfhi(u1.w)};
        a2[0] += nn2 * (f32x2){bflo(u2.x), bfhi(u2.x)};
        a2[1] += nn2 * (f32x2){bflo(u2.y), bfhi(u2.y)};
        a2[2] += nn2 * (f32x2){bflo(u2.z), bfhi(u2.z)};
        a2[3] += nn2 * (f32x2){bflo(u2.w), bfhi(u2.w)};
        a3[0] += nn3 * (f32x2){bflo(u3.x), bfhi(u3.x)};
        a3[1] += nn3 * (f32x2){bflo(u3.y), bfhi(u3.y)};
        a3[2] += nn3 * (f32x2){bflo(u3.z), bfhi(u3.z)};
        a3[3] += nn3 * (f32x2){bflo(u3.w), bfhi(u3.w)};
    }
    uint4 su = *(const uint4*)(xb + node * 16 + qoff);
    float dn2 = dn * dn;
    f32x2 nd = {dn2, dn2};
    a0[0] += nd * (f32x2){bflo(su.x), bfhi(su.x)};
    a0[1] += nd * (f32x2){bflo(su.y), bfhi(su.y)};
    a0[2] += nd * (f32x2){bflo(su.z), bfhi(su.z)};
    a0[3] += nd * (f32x2){bflo(su.w), bfhi(su.w)};
    float4 o0, o1;
    f32x2 s0 = (a0[0] + a1[0]) + (a2[0] + a3[0]);
    f32x2 s1 = (a0[1] + a1[1]) + (a2[1] + a3[1]);
    f32x2 s2 = (a0[2] + a1[2]) + (a2[2] + a3[2]);
    f32x2 s3 = (a0[3] + a1[3]) + (a2[3] + a3[3]);
    o0.x = s0[0]; o0.y = s0[1]; o0.z = s1[0]; o0.w = s1[1];
    o1.x = s2[0]; o1.y = s2[1]; o1.z = s3[0]; o1.w = s3[1];
    *(float4*)(aggx + node * 16 + qoff) = o0;
    *(float4*)(aggx + node * 16 + qoff + 4) = o1;  // wave: 32 rows x 64 B contiguous
}

// ---- h1 = relu(aggx[:, :12] @ W1 + b1) -> bf16 ----
__global__ void w1_kernel(const float* __restrict__ aggx, const float* __restrict__ W1,
                          const float* __restrict__ b1, unsigned short* __restrict__ h) {
    __shared__ float sW[IN_CH * HID];     // 3 KB
    __shared__ float sA[256];             // 16 nodes x 16 ch
    int tid = threadIdx.x;
    for (int i = tid; i < IN_CH * HID; i += 256) sW[i] = W1[i];
    int node0 = blockIdx.x * 16;
    sA[tid] = aggx[node0 * 16 + tid];
    __syncthreads();
    int nl = tid >> 4, c4 = (tid & 15) * 4;
    float a0 = 0, a1 = 0, a2 = 0, a3 = 0;
#pragma unroll
    for (int k = 0; k < IN_CH; k++) {
        float av = sA[nl * 16 + k];
        const float* w = &sW[k * HID + c4];
        a0 += av * w[0]; a1 += av * w[1]; a2 += av * w[2]; a3 += av * w[3];
    }
    const float* bb = &b1[c4];
    ushort4 v = {f2bf(fmaxf(a0 + bb[0], 0.0f)), f2bf(fmaxf(a1 + bb[1], 0.0f)),
                 f2bf(fmaxf(a2 + bb[2], 0.0f)), f2bf(fmaxf(a3 + bb[3], 0.0f))};
    *(ushort4*)&h[(node0 + nl) * HID + c4] = v;
}

// ---- layer-2 gather body: subgroup-private node; lane owns 8 channels ----
__device__ __forceinline__ void agg_body(int beg, int end, const int2* __restrict__ csr,
                                         const unsigned short* __restrict__ h,
                                         int qoff, float* r) {
    f32x2 a0[4] = {{0, 0}, {0, 0}, {0, 0}, {0, 0}};
    f32x2 a1[4] = {{0, 0}, {0, 0}, {0, 0}, {0, 0}};
    f32x2 a2[4] = {{0, 0}, {0, 0}, {0, 0}, {0, 0}};
    f32x2 a3[4] = {{0, 0}, {0, 0}, {0, 0}, {0, 0}};
    for (int j = beg; j < end; j += 4) {  // rows padded to x4: no remainder
        int4 e01 = *(const int4*)(csr + j);
        int4 e23 = *(const int4*)(csr + j + 2);
        uint4 u0 = *(const uint4*)(h + e01.x + qoff);
        uint4 u1 = *(const uint4*)(h + e01.z + qoff);
        uint4 u2 = *(const uint4*)(h + e23.x + qoff);
        uint4 u3 = *(const uint4*)(h + e23.z + qoff);
        float n0 = __int_as_float(e01.y), n1 = __int_as_float(e01.w);
        float n2 = __int_as_float(e23.y), n3 = __int_as_float(e23.w);
        f32x2 nn0 = {n0, n0}, nn1 = {n1, n1}, nn2 = {n2, n2}, nn3 = {n3, n3};
        a0[0] += nn0 * (f32x2){bflo(u0.x), bfhi(u0.x)};
        a0[1] += nn0 * (f32x2){bflo(u0.y), bfhi(u0.y)};
        a0[2] += nn0 * (f32x2){bflo(u0.z), bfhi(u0.z)};
        a0[3] += nn0 * (f32x2){bflo(u0.w), bfhi(u0.w)};
        a1[0] += nn1 * (f32x2){bflo(u1.x), bfhi(u1.x)};
        a1[1] += nn1 * (f32x2){bflo(u1.y), bfhi(u1.y)};
        a1[2] += nn1 * (f32x2){bflo(u1.z), bfhi(u1.z)};
        a1[3] += nn1 * (f32x2){bflo(u1.w), bfhi(u1.w)};
        a2[0] += nn2 * (f32x2){bflo(u2.x), bfhi(u2.x)};
        a2[1] += nn2 * (f32x2){bflo(u2.y), bfhi(u2.y)};
        a2[2] += nn2 * (f32x2){bflo(u2.z), bfhi(u2.z)};
        a2[3] += nn2 * (f32x2){bflo(u2.w), bfhi(u2.w)};
        a3[0] += nn3 * (f32x2){bflo(u3.x), bfhi(u3.x)};
        a3[1] += nn3 * (f32x2){bflo(u3.y), bfhi(u3.y)};
        a3[2] += nn3 * (f32x2){bflo(u3.z), bfhi(u3.z)};
        a3[3] += nn3 * (f32x2){bflo(u3.w), bfhi(u3.w)};
    }
#pragma unroll
    for (int k = 0; k < 4; k++) {
        f32x2 s = (a0[k] + a1[k]) + (a2[k] + a3[k]);
        r[2 * k] = s[0];
        r[2 * k + 1] = s[1];
    }
}

// ---- layer-2 gather-aggregate + relu + fused mean-pool (run-length flush) ----
__global__ void agg_pool_kernel(const int2* __restrict__ rowbounds, const int2* __restrict__ csr,
                                const float* __restrict__ dinv,
                                const unsigned short* __restrict__ h,
                                const float* __restrict__ b, const int* __restrict__ batch,
                                float* __restrict__ pool, float* __restrict__ gcnt) {
    __shared__ float red[32][HID];  // 8 KB
    __shared__ int gids[32];
    int tid = threadIdx.x;
    int w = tid >> 6, lane = tid & 63, sub = lane >> 3, q = lane & 7;
    int qoff = 8 * q;
    int node = (blockIdx.x * 4 + w) * 8 + sub;
    int2 rb = rowbounds[node];
    float dn = dinv[node];
    float r[8];
    agg_body(rb.x, rb.y, csr, h, qoff, r);
    uint4 su = *(const uint4*)(h + node * HID + qoff);
    float4 b0 = *(const float4*)&b[qoff];
    float4 b1 = *(const float4*)&b[qoff + 4];
    float dn2 = dn * dn;
    float4 v0, v1;
    v0.x = fmaxf(r[0] + dn2 * bflo(su.x) + b0.x, 0.0f);
    v0.y = fmaxf(r[1] + dn2 * bfhi(su.x) + b0.y, 0.0f);
    v0.z = fmaxf(r[2] + dn2 * bflo(su.y) + b0.z, 0.0f);
    v0.w = fmaxf(r[3] + dn2 * bfhi(su.y) + b0.w, 0.0f);
    v1.x = fmaxf(r[4] + dn2 * bflo(su.z) + b1.x, 0.0f);
    v1.y = fmaxf(r[5] + dn2 * bfhi(su.z) + b1.y, 0.0f);
    v1.z = fmaxf(r[6] + dn2 * bflo(su.w) + b1.z, 0.0f);
    v1.w = fmaxf(r[7] + dn2 * bfhi(su.w) + b1.w, 0.0f);
    int nl = w * 8 + sub;
    *(float4*)&red[nl][qoff] = v0;
    *(float4*)&red[nl][qoff + 4] = v1;
    if (q == 0) gids[nl] = batch[node];
    __syncthreads();
    if (tid < 64) {  // wave 0: run-length reduce 32 nodes (batch sorted)
        int c = tid;
        float acc = 0.0f;
        int cur = gids[0], cnt = 0;
        for (int n = 0; n < 32; n++) {
            int g = gids[n];
            if (g != cur) {
                atomicAdd(&pool[cur * HID + c], acc);
                if (c == 0) atomicAdd(&gcnt[cur], (float)cnt);
                acc = 0.0f; cnt = 0; cur = g;
            }
            acc += red[n][c];
            cnt++;
        }
        atomicAdd(&pool[cur * HID + c], acc);
        if (c == 0) atomicAdd(&gcnt[cur], (float)cnt);
    }
}

// ---- h @ W2 : [N,64] @ [64,64], bf16 in/out, fp32 compute ----
__global__ void hw2_kernel(const unsigned short* __restrict__ hin,
                           const float* __restrict__ W2, unsigned short* __restrict__ hout) {
    __shared__ float sW[HID * HID];
    __shared__ __align__(16) float sh[16 * HID];
    int tid = threadIdx.x;
    for (int i = tid; i < HID * HID; i += 256) sW[i] = W2[i];
    int node0 = blockIdx.x * 16;
    {
        uint2 u = *(const uint2*)&hin[node0 * HID + 4 * tid];
        sh[4 * tid + 0] = bflo(u.x); sh[4 * tid + 1] = bfhi(u.x);
        sh[4 * tid + 2] = bflo(u.y); sh[4 * tid + 3] = bfhi(u.y);
    }
    __syncthreads();
    int nl = tid >> 4, c4 = (tid & 15) * 4;
    float a0 = 0, a1 = 0, a2 = 0, a3 = 0;
#pragma unroll 8
    for (int k = 0; k < HID; k++) {
        float hv = sh[nl * HID + k];
        float4 w = *(const float4*)&sW[k * HID + c4];
        a0 += hv * w.x; a1 += hv * w.y; a2 += hv * w.z; a3 += hv * w.w;
    }
    ushort4 v = {f2bf(a0), f2bf(a1), f2bf(a2), f2bf(a3)};
    *(ushort4*)&hout[(node0 + nl) * HID + c4] = v;
}

// ---- final: out = sigmoid((pool/cnt) @ Wfc + bfc) ----
__global__ void final_kernel(const float* __restrict__ pool, const float* __restrict__ gcnt,
                             const float* __restrict__ Wfc, const float* __restrict__ bfc,
                             float* __restrict__ out) {
    int idx = blockIdx.x * 256 + threadIdx.x;
    if (idx >= N_GRAPHS * OUT_CH) return;
    int g = idx >> 2, o = idx & 3;
    float inv = 1.0f / fmaxf(gcnt[g], 1.0f);
    float acc = bfc[o];
#pragma unroll
    for (int k = 0; k < HID; k++) acc += pool[g * HID + k] * inv * Wfc[k * OUT_CH + o];
    out[idx] = 1.0f / (1.0f + expf(-acc));
}

extern "C" void kernel_launch(void* const* d_in, const int* in_sizes, int n_in,
                              void* d_out, int out_size, void* d_ws, size_t ws_size,
                              hipStream_t stream) {
    const float* x   = (const float*)d_in[0];
    const int* eidx  = (const int*)d_in[1];
    const int* batch = (const int*)d_in[2];
    const float* W1  = (const float*)d_in[3];
    const float* b1  = (const float*)d_in[4];
    const float* W2  = (const float*)d_in[5];
    const float* b2  = (const float*)d_in[6];
    const float* Wfc = (const float*)d_in[7];
    const float* bfc = (const float*)d_in[8];
    float* out = (float*)d_out;

    const int* src = eidx;
    const int* dst = eidx + N_EDGES;

    // workspace layout (~77 MB)
    unsigned short* hA = (unsigned short*)d_ws;              // 16 MB bf16 (h1)
    unsigned short* hB = hA + (size_t)N_NODES * HID;         // 16 MB bf16 (h1@W2)
    int2*  csr    = (int2*)(hB + (size_t)N_NODES * HID);     // 21 MB {src<<6, norm}
    int*   staged = (int*)(csr + (size_t)NBUCK * CSR_STRIDE); // 9.4 MB bucket-strided
    float* dinv   = (float*)(staged + (size_t)NBUCK * STRIDE); // 512 KB
    int2*  rowbounds = (int2*)(dinv + N_NODES);              // 1 MB
    int*   bucket_count = (int*)(rowbounds + N_NODES);       // 2 KB
    float* pool   = (float*)(bucket_count + NBUCK);          // 512 KB
    float* gcnt   = pool + N_GRAPHS * HID;                   // 8 KB
    unsigned short* xb = (unsigned short*)(gcnt + N_GRAPHS); // 4 MB bf16 [N,16]
    float* aggx   = (float*)(xb + (size_t)N_NODES * 16);     // 8 MB fp32 [N,16]

    hipMemsetAsync(bucket_count, 0, (size_t)NBUCK * 4, stream);
    hipMemsetAsync(pool, 0, (size_t)(N_GRAPHS * HID + N_GRAPHS) * 4, stream);

    // CSR build: bucket sort -> padded rowbounds/dinv -> ordered fill (+pads)
    bucket_kernel<<<N_EDGES / CHUNK, 1024, 0, stream>>>(src, dst, bucket_count, staged);
    count_kernel<<<NBUCK, 256, 0, stream>>>(bucket_count, staged, rowbounds, dinv);
    place_kernel<<<NBUCK, 256, 0, stream>>>(bucket_count, staged, rowbounds, dinv, csr);

    // layer 1: agg(x) @ W1 (aggregation commutes with the linear map)
    xcast_kernel<<<N_NODES / 256, 256, 0, stream>>>(x, xb);
    agg_x_kernel<<<N_NODES / 128, 256, 0, stream>>>(rowbounds, csr, dinv, xb, aggx);
    w1_kernel<<<N_NODES / 16, 256, 0, stream>>>(aggx, W1, b1, hA);

    // layer 2 (pool fused; h2 never materialized)
    hw2_kernel<<<N_NODES / 16, 256, 0, stream>>>(hA, W2, hB);
    agg_pool_kernel<<<N_NODES / 32, 256, 0, stream>>>(rowbounds, csr, dinv, hB, b2, batch,
                                                      pool, gcnt);

    // head
    final_kernel<<<(N_GRAPHS * OUT_CH + 255) / 256, 256, 0, stream>>>(pool, gcnt, Wfc, bfc, out);
}